// Round 1
// baseline (5831.880 us; speedup 1.0000x reference)
//
#include <hip/hip_runtime.h>

#define EPSV 1e-5f
#define HDIM 128

// ---------------- degree / dinv ----------------
__global__ __launch_bounds__(256) void count_deg(const int* __restrict__ dst,
                                                 float* __restrict__ deg, int E) {
    int e = blockIdx.x * 256 + threadIdx.x;
    if (e < E) unsafeAtomicAdd(&deg[dst[e]], 1.0f);
}

__global__ __launch_bounds__(256) void make_dinv(float* __restrict__ deg, int N) {
    int i = blockIdx.x * 256 + threadIdx.x;
    if (i < N) deg[i] = 1.0f / sqrtf(deg[i] + 1.0f);
}

// ---------------- input matmul: hs = dinv * (x @ W1), dup into accum ----------------
__global__ __launch_bounds__(256) void mm_in(const float* __restrict__ x,
                                             const float* __restrict__ W,
                                             const float* __restrict__ dinv,
                                             float* __restrict__ A,
                                             float* __restrict__ B, int N) {
    __shared__ float ws[7 * HDIM];
    int t = threadIdx.x;
    for (int i = t; i < 7 * HDIM; i += 256) ws[i] = W[i];
    __syncthreads();
    long long idx = (long long)blockIdx.x * 256 + t;
    if (idx >= (long long)N * HDIM) return;
    int n = (int)(idx >> 7), c = (int)(idx & 127);
    const float* xr = x + (long long)n * 7;
    float s = 0.f;
#pragma unroll
    for (int k = 0; k < 7; k++) s += xr[k] * ws[k * HDIM + c];
    float v = s * dinv[n];
    A[idx] = v;
    B[idx] = v;
}

// ---------------- edge aggregation: B[dst] += A[src] (one wave per edge) ----------------
__global__ __launch_bounds__(256) void edge_agg(const int* __restrict__ src,
                                                const int* __restrict__ dst,
                                                const float* __restrict__ A,
                                                float* __restrict__ B, int E) {
    int wave = (int)((blockIdx.x * 256 + threadIdx.x) >> 6);
    int lane = threadIdx.x & 63;
    if (wave >= E) return;
    int s = src[wave], d = dst[wave];
    const float2 v = *(const float2*)(A + (long long)s * HDIM + lane * 2);
    float* out = B + (long long)d * HDIM + lane * 2;
    unsafeAtomicAdd(out, v.x);
    unsafeAtomicAdd(out + 1, v.y);
}

// ---------------- count nodes per graph ----------------
__global__ __launch_bounds__(256) void count_nodes(const int* __restrict__ batch,
                                                   float* __restrict__ gcnt, int N) {
    int i = blockIdx.x * 256 + threadIdx.x;
    if (i < N) unsafeAtomicAdd(&gcnt[batch[i]], 1.0f);
}

// ---------------- v = dinv*accum + bias ; write A ; atomically accumulate per-graph sums ----------------
__global__ __launch_bounds__(256) void fix_sum(const float* __restrict__ Bacc,
                                               const float* __restrict__ dinv,
                                               const float* __restrict__ bias,
                                               const int* __restrict__ batch,
                                               float* __restrict__ A,
                                               float* __restrict__ gsum, int N) {
    long long idx = (long long)blockIdx.x * 256 + threadIdx.x;
    if (idx >= (long long)N * HDIM) return;
    int n = (int)(idx >> 7), c = (int)(idx & 127);
    float v = Bacc[idx] * dinv[n] + bias[c];
    A[idx] = v;
    unsafeAtomicAdd(&gsum[(long long)batch[n] * HDIM + c], v);
}

// ---------------- divide per-graph accum by count ----------------
__global__ __launch_bounds__(256) void seg_div(float* __restrict__ buf,
                                               const float* __restrict__ gcnt, int total) {
    int i = blockIdx.x * 256 + threadIdx.x;
    if (i < total) buf[i] /= fmaxf(gcnt[i >> 7], 1.0f);
}

// ---------------- variance accumulation ----------------
__global__ __launch_bounds__(256) void var_sum(const float* __restrict__ A,
                                               const float* __restrict__ alpha,
                                               const float* __restrict__ gmean,
                                               const int* __restrict__ batch,
                                               float* __restrict__ gvar, int N) {
    long long idx = (long long)blockIdx.x * 256 + threadIdx.x;
    if (idx >= (long long)N * HDIM) return;
    int n = (int)(idx >> 7), c = (int)(idx & 127);
    int b = batch[n];
    float d = A[idx] - alpha[c] * gmean[(long long)b * HDIM + c];
    unsafeAtomicAdd(&gvar[(long long)b * HDIM + c], d * d);
}

// ---------------- normalize + relu ----------------
__global__ __launch_bounds__(256) void norm_relu(const float* __restrict__ A,
                                                 const float* __restrict__ gmean,
                                                 const float* __restrict__ gvar,
                                                 const float* __restrict__ alpha,
                                                 const float* __restrict__ w,
                                                 const float* __restrict__ bb,
                                                 const int* __restrict__ batch,
                                                 float* __restrict__ out, int N) {
    long long idx = (long long)blockIdx.x * 256 + threadIdx.x;
    if (idx >= (long long)N * HDIM) return;
    int n = (int)(idx >> 7), c = (int)(idx & 127);
    int b = batch[n];
    float m = gmean[(long long)b * HDIM + c];
    float var = gvar[(long long)b * HDIM + c];
    float d = A[idx] - alpha[c] * m;
    float y = w[c] * d * rsqrtf(var + EPSV) + bb[c];
    out[idx] = fmaxf(y, 0.f);
}

// ---------------- hidden matmul: out = dinv * (X @ W), X [N,128], W [128,128] ----------------
__global__ __launch_bounds__(256) void mm_h(const float* __restrict__ X,
                                            const float* __restrict__ W,
                                            const float* __restrict__ dinv,
                                            float* __restrict__ out, int N) {
    __shared__ float xs[64][65];                    // [node][k-half]
    __shared__ __align__(16) float ws[64][HDIM];    // [k-half][c]
    int t = threadIdx.x;
    int tx = t & 15;   // c-group: channels tx*4..tx*4+3 and 64+tx*4..64+tx*4+3
    int ty = t >> 4;   // n-group: nodes ty*4..ty*4+3
    int n0 = blockIdx.x * 64;
    float acc[4][8];
#pragma unroll
    for (int i = 0; i < 4; i++)
#pragma unroll
        for (int j = 0; j < 8; j++) acc[i][j] = 0.f;

    for (int s = 0; s < 2; ++s) {
        __syncthreads();
        // stage x half: 64 nodes x 64 k
        for (int i = t; i < 64 * 16; i += 256) {
            int nn = i >> 4;
            int kk = (i & 15) * 4;
            int gn = n0 + nn;
            float4 v = make_float4(0.f, 0.f, 0.f, 0.f);
            if (gn < N) v = *(const float4*)(X + (long long)gn * HDIM + s * 64 + kk);
            xs[nn][kk] = v.x; xs[nn][kk + 1] = v.y; xs[nn][kk + 2] = v.z; xs[nn][kk + 3] = v.w;
        }
        // stage W half: 64 k x 128 c
        for (int i = t; i < 64 * 32; i += 256) {
            int kk = i >> 5;
            int c = (i & 31) * 4;
            *(float4*)&ws[kk][c] = *(const float4*)(W + (long long)(s * 64 + kk) * HDIM + c);
        }
        __syncthreads();
#pragma unroll 8
        for (int kk = 0; kk < 64; ++kk) {
            float xv[4];
#pragma unroll
            for (int i = 0; i < 4; i++) xv[i] = xs[ty * 4 + i][kk];
            float4 w0 = *(const float4*)&ws[kk][tx * 4];
            float4 w1 = *(const float4*)&ws[kk][64 + tx * 4];
#pragma unroll
            for (int i = 0; i < 4; i++) {
                acc[i][0] += xv[i] * w0.x; acc[i][1] += xv[i] * w0.y;
                acc[i][2] += xv[i] * w0.z; acc[i][3] += xv[i] * w0.w;
                acc[i][4] += xv[i] * w1.x; acc[i][5] += xv[i] * w1.y;
                acc[i][6] += xv[i] * w1.z; acc[i][7] += xv[i] * w1.w;
            }
        }
    }
#pragma unroll
    for (int i = 0; i < 4; i++) {
        int gn = n0 + ty * 4 + i;
        if (gn >= N) continue;
        float dv = dinv[gn];
        float4 o0 = make_float4(acc[i][0] * dv, acc[i][1] * dv, acc[i][2] * dv, acc[i][3] * dv);
        float4 o1 = make_float4(acc[i][4] * dv, acc[i][5] * dv, acc[i][6] * dv, acc[i][7] * dv);
        *(float4*)(out + (long long)gn * HDIM + tx * 4) = o0;
        *(float4*)(out + (long long)gn * HDIM + 64 + tx * 4) = o1;
    }
}

// ---------------- pool accumulation ----------------
__global__ __launch_bounds__(256) void pool_sum(const float* __restrict__ X,
                                                const int* __restrict__ batch,
                                                float* __restrict__ gsum, int N) {
    long long idx = (long long)blockIdx.x * 256 + threadIdx.x;
    if (idx >= (long long)N * HDIM) return;
    int n = (int)(idx >> 7), c = (int)(idx & 127);
    unsafeAtomicAdd(&gsum[(long long)batch[n] * HDIM + c], X[idx]);
}

// ---------------- head: g = pool/cnt ; t = relu(g@H1+hb1) ; out = t@H2+hb2 ----------------
__global__ __launch_bounds__(128) void head(const float* __restrict__ gsum,
                                            const float* __restrict__ gcnt,
                                            const float* __restrict__ H1,
                                            const float* __restrict__ hb1,
                                            const float* __restrict__ H2,
                                            const float* __restrict__ hb2,
                                            float* __restrict__ out, int G) {
    __shared__ float gv[HDIM];
    __shared__ float tv[HDIM];
    __shared__ float r0[HDIM], r1[HDIM];
    int g = blockIdx.x;
    int c = threadIdx.x;
    float cnt = fmaxf(gcnt[g], 1.0f);
    gv[c] = gsum[(long long)g * HDIM + c] / cnt;
    __syncthreads();
    float s = hb1[c];
    for (int k = 0; k < HDIM; k++) s += gv[k] * H1[k * HDIM + c];
    tv[c] = fmaxf(s, 0.f);
    __syncthreads();
    r0[c] = tv[c] * H2[c * 2 + 0];
    r1[c] = tv[c] * H2[c * 2 + 1];
    __syncthreads();
    for (int off = 64; off > 0; off >>= 1) {
        if (c < off) { r0[c] += r0[c + off]; r1[c] += r1[c + off]; }
        __syncthreads();
    }
    if (c == 0) {
        out[(long long)g * 2 + 0] = r0[0] + hb2[0];
        out[(long long)g * 2 + 1] = r1[0] + hb2[1];
    }
}

extern "C" void kernel_launch(void* const* d_in, const int* in_sizes, int n_in,
                              void* d_out, int out_size, void* d_ws, size_t ws_size,
                              hipStream_t stream) {
    const float* x    = (const float*)d_in[0];
    const int*   ei   = (const int*)d_in[1];
    const int*   batch= (const int*)d_in[2];
    const float* W1   = (const float*)d_in[4];
    const float* b1   = (const float*)d_in[5];
    const float* gn1w = (const float*)d_in[6];
    const float* gn1b = (const float*)d_in[7];
    const float* gn1a = (const float*)d_in[8];
    const float* W2   = (const float*)d_in[9];
    const float* b2   = (const float*)d_in[10];
    const float* gn2w = (const float*)d_in[11];
    const float* gn2b = (const float*)d_in[12];
    const float* gn2a = (const float*)d_in[13];
    const float* H1   = (const float*)d_in[14];
    const float* hb1  = (const float*)d_in[15];
    const float* H2   = (const float*)d_in[16];
    const float* hb2  = (const float*)d_in[17];

    int N = in_sizes[0] / 7;
    int E = in_sizes[1] / 2;
    int G = out_size / 2;
    const int* srcI = ei;
    const int* dstI = ei + E;

    float* wsp  = (float*)d_ws;
    float* dinv = wsp;                          // N
    float* A    = dinv + N;                     // N*128
    float* Bb   = A + (size_t)N * HDIM;         // N*128
    float* gsum = Bb + (size_t)N * HDIM;        // G*128
    float* gvar = gsum + (size_t)G * HDIM;      // G*128
    float* gcnt = gvar + (size_t)G * HDIM;      // G

    long long NH = (long long)N * HDIM;
    int gridNH = (int)((NH + 255) / 256);
    int gridN  = (N + 255) / 256;
    int gridE  = (E + 255) / 256;
    int gridEw = (E + 3) / 4;       // 4 waves (edges) per 256-thread block
    int gridGH = (G * HDIM + 255) / 256;
    int gridMM = (N + 63) / 64;

    // degree -> dinv
    hipMemsetAsync(dinv, 0, (size_t)N * 4, stream);
    count_deg<<<gridE, 256, 0, stream>>>(dstI, dinv, E);
    make_dinv<<<gridN, 256, 0, stream>>>(dinv, N);

    // node counts per graph (shared by both norms + pool)
    hipMemsetAsync(gcnt, 0, (size_t)G * 4, stream);
    count_nodes<<<gridN, 256, 0, stream>>>(batch, gcnt, N);

    // ---- block 1 ----
    mm_in<<<gridNH, 256, 0, stream>>>(x, W1, dinv, A, Bb, N);
    edge_agg<<<gridEw, 256, 0, stream>>>(srcI, dstI, A, Bb, E);
    hipMemsetAsync(gsum, 0, (size_t)G * HDIM * 4, stream);
    fix_sum<<<gridNH, 256, 0, stream>>>(Bb, dinv, b1, batch, A, gsum, N);
    seg_div<<<gridGH, 256, 0, stream>>>(gsum, gcnt, G * HDIM);
    hipMemsetAsync(gvar, 0, (size_t)G * HDIM * 4, stream);
    var_sum<<<gridNH, 256, 0, stream>>>(A, gn1a, gsum, batch, gvar, N);
    seg_div<<<gridGH, 256, 0, stream>>>(gvar, gcnt, G * HDIM);
    norm_relu<<<gridNH, 256, 0, stream>>>(A, gsum, gvar, gn1a, gn1w, gn1b, batch, Bb, N);

    // ---- block 2 ----
    mm_h<<<gridMM, 256, 0, stream>>>(Bb, W2, dinv, A, N);
    hipMemcpyAsync(Bb, A, (size_t)NH * 4, hipMemcpyDeviceToDevice, stream);
    edge_agg<<<gridEw, 256, 0, stream>>>(srcI, dstI, A, Bb, E);
    hipMemsetAsync(gsum, 0, (size_t)G * HDIM * 4, stream);
    fix_sum<<<gridNH, 256, 0, stream>>>(Bb, dinv, b2, batch, A, gsum, N);
    seg_div<<<gridGH, 256, 0, stream>>>(gsum, gcnt, G * HDIM);
    hipMemsetAsync(gvar, 0, (size_t)G * HDIM * 4, stream);
    var_sum<<<gridNH, 256, 0, stream>>>(A, gn2a, gsum, batch, gvar, N);
    seg_div<<<gridGH, 256, 0, stream>>>(gvar, gcnt, G * HDIM);
    norm_relu<<<gridNH, 256, 0, stream>>>(A, gsum, gvar, gn2a, gn2w, gn2b, batch, Bb, N);

    // ---- pool + head ----
    hipMemsetAsync(gsum, 0, (size_t)G * HDIM * 4, stream);
    pool_sum<<<gridNH, 256, 0, stream>>>(Bb, batch, gsum, N);
    head<<<G, 128, 0, stream>>>(gsum, gcnt, H1, hb1, H2, hb2, (float*)d_out, G);
}

// Round 2
// 1112.722 us; speedup vs baseline: 5.2411x; 5.2411x over previous
//
#include <hip/hip_runtime.h>

#define EPSV 1e-5f
#define HDIM 128

// ---------------- degree count (int) ----------------
__global__ __launch_bounds__(256) void count_deg_i(const int* __restrict__ dst,
                                                   int* __restrict__ deg, int E) {
    int e = blockIdx.x * 256 + threadIdx.x;
    if (e < E) atomicAdd(&deg[dst[e]], 1);
}

// ---------------- 2-level exclusive scan for CSR row starts ----------------
__global__ __launch_bounds__(256) void scan_blk(const int* __restrict__ deg,
                                                int* __restrict__ rowPart,
                                                int* __restrict__ blkSum, int N) {
    __shared__ int tmp[256];
    int tid = threadIdx.x;
    int i = blockIdx.x * 256 + tid;
    int v = (i < N) ? deg[i] : 0;
    tmp[tid] = v;
    __syncthreads();
    for (int off = 1; off < 256; off <<= 1) {
        int t = (tid >= off) ? tmp[tid - off] : 0;
        __syncthreads();
        tmp[tid] += t;
        __syncthreads();
    }
    if (i < N) rowPart[i] = tmp[tid];            // within-block inclusive
    if (tid == 255) blkSum[blockIdx.x] = tmp[255];
}

__global__ __launch_bounds__(512) void scan_top(int* __restrict__ blkSum, int nblk) {
    __shared__ int tmp[512];
    int tid = threadIdx.x;
    int v = (tid < nblk) ? blkSum[tid] : 0;
    tmp[tid] = v;
    __syncthreads();
    for (int off = 1; off < 512; off <<= 1) {
        int t = (tid >= off) ? tmp[tid - off] : 0;
        __syncthreads();
        tmp[tid] += t;
        __syncthreads();
    }
    if (tid < nblk) blkSum[tid] = tmp[tid];      // inclusive over block sums
}

__global__ __launch_bounds__(256) void finalize_rows(int* __restrict__ rowStart,
                                                     const int* __restrict__ deg,
                                                     const int* __restrict__ blkSum, int N) {
    int i = blockIdx.x * 256 + threadIdx.x;
    if (i < N) {
        int b = i >> 8;
        int off = b ? blkSum[b - 1] : 0;
        rowStart[i] = rowStart[i] - deg[i] + off;   // exclusive scan value
        if (i == N - 1) rowStart[N] = blkSum[(N + 255) / 256 - 1];
    }
}

__global__ __launch_bounds__(256) void make_dinv(const int* __restrict__ deg,
                                                 float* __restrict__ dinv, int N) {
    int i = blockIdx.x * 256 + threadIdx.x;
    if (i < N) dinv[i] = rsqrtf((float)deg[i] + 1.0f);
}

__global__ __launch_bounds__(256) void scatter_edges(const int* __restrict__ src,
                                                     const int* __restrict__ dst,
                                                     const int* __restrict__ rowStart,
                                                     int* __restrict__ cursor,
                                                     int* __restrict__ col, int E) {
    int e = blockIdx.x * 256 + threadIdx.x;
    if (e < E) {
        int d = dst[e];
        int slot = rowStart[d] + atomicAdd(&cursor[d], 1);
        col[slot] = src[e];
    }
}

// ---------------- count nodes per graph ----------------
__global__ __launch_bounds__(256) void count_nodes(const int* __restrict__ batch,
                                                   float* __restrict__ gcnt, int N) {
    int i = blockIdx.x * 256 + threadIdx.x;
    if (i < N) unsafeAtomicAdd(&gcnt[batch[i]], 1.0f);
}

// ---------------- input matmul: P = dinv * (x @ W1) ----------------
__global__ __launch_bounds__(256) void mm_in(const float* __restrict__ x,
                                             const float* __restrict__ W,
                                             const float* __restrict__ dinv,
                                             float* __restrict__ P, int N) {
    __shared__ float ws[7 * HDIM];
    int t = threadIdx.x;
    for (int i = t; i < 7 * HDIM; i += 256) ws[i] = W[i];
    __syncthreads();
    long long idx = (long long)blockIdx.x * 256 + t;
    if (idx >= (long long)N * HDIM) return;
    int n = (int)(idx >> 7), c = (int)(idx & 127);
    const float* xr = x + (long long)n * 7;
    float s = 0.f;
#pragma unroll
    for (int k = 0; k < 7; k++) s += xr[k] * ws[k * HDIM + c];
    P[idx] = s * dinv[n];
}

// ---------------- CSR gather aggregation + bias + stats (wave per node) ----------------
__global__ __launch_bounds__(256) void node_agg(const int* __restrict__ col,
                                                const int* __restrict__ rowStart,
                                                const float* __restrict__ Ain,
                                                const float* __restrict__ dinv,
                                                const float* __restrict__ bias,
                                                const int* __restrict__ batch,
                                                float* __restrict__ Aout,
                                                float* __restrict__ gsum,
                                                float* __restrict__ gsq, int N) {
    __shared__ float sv[4][HDIM];
    __shared__ float sq[4][HDIM];
    __shared__ int bsh[4];
    int wib = threadIdx.x >> 6, lane = threadIdx.x & 63;
    int c = lane * 2;
    int n = blockIdx.x * 4 + wib;
    bool active = (n < N);
    float2 acc = make_float2(0.f, 0.f);
    int b = -1;
    if (active) {
        b = batch[n];
        acc = *(const float2*)(Ain + (size_t)n * HDIM + c);   // self term (hs[n])
        int rs = rowStart[n], re = rowStart[n + 1];
        int j = rs;
        for (; j + 1 < re; j += 2) {
            int s0 = col[j], s1 = col[j + 1];
            float2 t0 = *(const float2*)(Ain + (size_t)s0 * HDIM + c);
            float2 t1 = *(const float2*)(Ain + (size_t)s1 * HDIM + c);
            acc.x += t0.x + t1.x;
            acc.y += t0.y + t1.y;
        }
        if (j < re) {
            int s0 = col[j];
            float2 t0 = *(const float2*)(Ain + (size_t)s0 * HDIM + c);
            acc.x += t0.x;
            acc.y += t0.y;
        }
        float dv = dinv[n];
        acc.x = acc.x * dv + bias[c];
        acc.y = acc.y * dv + bias[c + 1];
        *(float2*)(Aout + (size_t)n * HDIM + c) = acc;
    }
    if (lane == 0) bsh[wib] = active ? b : -1;
    sv[wib][c] = acc.x;     sv[wib][c + 1] = acc.y;
    sq[wib][c] = acc.x * acc.x; sq[wib][c + 1] = acc.y * acc.y;
    __syncthreads();
    int b0 = bsh[0];
    bool uni = (b0 >= 0) && (bsh[1] == b0) && (bsh[2] == b0) && (bsh[3] == b0);
    if (uni) {
        if (wib == 0) {
            float vx = sv[0][c] + sv[1][c] + sv[2][c] + sv[3][c];
            float vy = sv[0][c + 1] + sv[1][c + 1] + sv[2][c + 1] + sv[3][c + 1];
            float qx = sq[0][c] + sq[1][c] + sq[2][c] + sq[3][c];
            float qy = sq[0][c + 1] + sq[1][c + 1] + sq[2][c + 1] + sq[3][c + 1];
            unsafeAtomicAdd(&gsum[(size_t)b0 * HDIM + c], vx);
            unsafeAtomicAdd(&gsum[(size_t)b0 * HDIM + c + 1], vy);
            unsafeAtomicAdd(&gsq[(size_t)b0 * HDIM + c], qx);
            unsafeAtomicAdd(&gsq[(size_t)b0 * HDIM + c + 1], qy);
        }
    } else if (active) {
        unsafeAtomicAdd(&gsum[(size_t)b * HDIM + c], acc.x);
        unsafeAtomicAdd(&gsum[(size_t)b * HDIM + c + 1], acc.y);
        unsafeAtomicAdd(&gsq[(size_t)b * HDIM + c], acc.x * acc.x);
        unsafeAtomicAdd(&gsq[(size_t)b * HDIM + c + 1], acc.y * acc.y);
    }
}

// ---------------- per-(graph,channel): sums -> mean, inv-std ----------------
__global__ __launch_bounds__(256) void gstat(float* __restrict__ gsum,
                                             float* __restrict__ gsq,
                                             const float* __restrict__ gcnt,
                                             const float* __restrict__ alpha, int total) {
    int i = blockIdx.x * 256 + threadIdx.x;
    if (i < total) {
        int g = i >> 7, c = i & 127;
        float cnt = fmaxf(gcnt[g], 1.f);
        float mean = gsum[i] / cnt;
        float m2 = gsq[i] / cnt;
        float a = alpha[c];
        // var of (x - a*mean) = E[x^2] - 2a*mean*E[x] + a^2*mean^2
        float var = m2 + mean * mean * (a * a - 2.f * a);
        gsum[i] = mean;
        gsq[i] = rsqrtf(fmaxf(var, 0.f) + EPSV);
    }
}

// ---------------- normalize + relu (elementwise, write out) ----------------
__global__ __launch_bounds__(256) void norm_relu(const float* __restrict__ X,
                                                 const float* __restrict__ gmean,
                                                 const float* __restrict__ gistd,
                                                 const float* __restrict__ alpha,
                                                 const float* __restrict__ w,
                                                 const float* __restrict__ bb,
                                                 const int* __restrict__ batch,
                                                 float* __restrict__ out, int N) {
    long long idx = (long long)blockIdx.x * 256 + threadIdx.x;
    if (idx >= (long long)N * HDIM) return;
    int n = (int)(idx >> 7), c = (int)(idx & 127);
    int b = batch[n];
    float m = gmean[(long long)b * HDIM + c];
    float is = gistd[(long long)b * HDIM + c];
    float d = X[idx] - alpha[c] * m;
    out[idx] = fmaxf(w[c] * d * is + bb[c], 0.f);
}

// ---------------- hidden matmul: out = dinv * (X @ W) ----------------
__global__ __launch_bounds__(256) void mm_h(const float* __restrict__ X,
                                            const float* __restrict__ W,
                                            const float* __restrict__ dinv,
                                            float* __restrict__ out, int N) {
    __shared__ float xs[64][65];
    __shared__ __align__(16) float ws[64][HDIM];
    int t = threadIdx.x;
    int tx = t & 15;
    int ty = t >> 4;
    int n0 = blockIdx.x * 64;
    float acc[4][8];
#pragma unroll
    for (int i = 0; i < 4; i++)
#pragma unroll
        for (int j = 0; j < 8; j++) acc[i][j] = 0.f;

    for (int s = 0; s < 2; ++s) {
        __syncthreads();
        for (int i = t; i < 64 * 16; i += 256) {
            int nn = i >> 4;
            int kk = (i & 15) * 4;
            int gn = n0 + nn;
            float4 v = make_float4(0.f, 0.f, 0.f, 0.f);
            if (gn < N) v = *(const float4*)(X + (long long)gn * HDIM + s * 64 + kk);
            xs[nn][kk] = v.x; xs[nn][kk + 1] = v.y; xs[nn][kk + 2] = v.z; xs[nn][kk + 3] = v.w;
        }
        for (int i = t; i < 64 * 32; i += 256) {
            int kk = i >> 5;
            int c = (i & 31) * 4;
            *(float4*)&ws[kk][c] = *(const float4*)(W + (long long)(s * 64 + kk) * HDIM + c);
        }
        __syncthreads();
#pragma unroll 8
        for (int kk = 0; kk < 64; ++kk) {
            float xv[4];
#pragma unroll
            for (int i = 0; i < 4; i++) xv[i] = xs[ty * 4 + i][kk];
            float4 w0 = *(const float4*)&ws[kk][tx * 4];
            float4 w1 = *(const float4*)&ws[kk][64 + tx * 4];
#pragma unroll
            for (int i = 0; i < 4; i++) {
                acc[i][0] += xv[i] * w0.x; acc[i][1] += xv[i] * w0.y;
                acc[i][2] += xv[i] * w0.z; acc[i][3] += xv[i] * w0.w;
                acc[i][4] += xv[i] * w1.x; acc[i][5] += xv[i] * w1.y;
                acc[i][6] += xv[i] * w1.z; acc[i][7] += xv[i] * w1.w;
            }
        }
    }
#pragma unroll
    for (int i = 0; i < 4; i++) {
        int gn = n0 + ty * 4 + i;
        if (gn >= N) continue;
        float dv = dinv[gn];
        float4 o0 = make_float4(acc[i][0] * dv, acc[i][1] * dv, acc[i][2] * dv, acc[i][3] * dv);
        float4 o1 = make_float4(acc[i][4] * dv, acc[i][5] * dv, acc[i][6] * dv, acc[i][7] * dv);
        *(float4*)(out + (long long)gn * HDIM + tx * 4) = o0;
        *(float4*)(out + (long long)gn * HDIM + 64 + tx * 4) = o1;
    }
}

// ---------------- layer-2 normalize+relu fused with pool atomics (wave per node) ----------------
__global__ __launch_bounds__(256) void node_norm_pool(const float* __restrict__ X,
                                                      const float* __restrict__ gmean,
                                                      const float* __restrict__ gistd,
                                                      const float* __restrict__ alpha,
                                                      const float* __restrict__ w,
                                                      const float* __restrict__ bb,
                                                      const int* __restrict__ batch,
                                                      float* __restrict__ gpool, int N) {
    __shared__ float sv[4][HDIM];
    __shared__ int bsh[4];
    int wib = threadIdx.x >> 6, lane = threadIdx.x & 63;
    int c = lane * 2;
    int n = blockIdx.x * 4 + wib;
    bool active = (n < N);
    float2 y = make_float2(0.f, 0.f);
    int b = -1;
    if (active) {
        b = batch[n];
        float2 v = *(const float2*)(X + (size_t)n * HDIM + c);
        float2 m = *(const float2*)(gmean + (size_t)b * HDIM + c);
        float2 is = *(const float2*)(gistd + (size_t)b * HDIM + c);
        y.x = fmaxf(w[c] * (v.x - alpha[c] * m.x) * is.x + bb[c], 0.f);
        y.y = fmaxf(w[c + 1] * (v.y - alpha[c + 1] * m.y) * is.y + bb[c + 1], 0.f);
    }
    if (lane == 0) bsh[wib] = active ? b : -1;
    sv[wib][c] = y.x; sv[wib][c + 1] = y.y;
    __syncthreads();
    int b0 = bsh[0];
    bool uni = (b0 >= 0) && (bsh[1] == b0) && (bsh[2] == b0) && (bsh[3] == b0);
    if (uni) {
        if (wib == 0) {
            float vx = sv[0][c] + sv[1][c] + sv[2][c] + sv[3][c];
            float vy = sv[0][c + 1] + sv[1][c + 1] + sv[2][c + 1] + sv[3][c + 1];
            unsafeAtomicAdd(&gpool[(size_t)b0 * HDIM + c], vx);
            unsafeAtomicAdd(&gpool[(size_t)b0 * HDIM + c + 1], vy);
        }
    } else if (active) {
        unsafeAtomicAdd(&gpool[(size_t)b * HDIM + c], y.x);
        unsafeAtomicAdd(&gpool[(size_t)b * HDIM + c + 1], y.y);
    }
}

// ---------------- head ----------------
__global__ __launch_bounds__(128) void head(const float* __restrict__ gpool,
                                            const float* __restrict__ gcnt,
                                            const float* __restrict__ H1,
                                            const float* __restrict__ hb1,
                                            const float* __restrict__ H2,
                                            const float* __restrict__ hb2,
                                            float* __restrict__ out, int G) {
    __shared__ float gv[HDIM];
    __shared__ float tv[HDIM];
    __shared__ float r0[HDIM], r1[HDIM];
    int g = blockIdx.x;
    int c = threadIdx.x;
    float cnt = fmaxf(gcnt[g], 1.0f);
    gv[c] = gpool[(long long)g * HDIM + c] / cnt;
    __syncthreads();
    float s = hb1[c];
    for (int k = 0; k < HDIM; k++) s += gv[k] * H1[k * HDIM + c];
    tv[c] = fmaxf(s, 0.f);
    __syncthreads();
    r0[c] = tv[c] * H2[c * 2 + 0];
    r1[c] = tv[c] * H2[c * 2 + 1];
    __syncthreads();
    for (int off = 64; off > 0; off >>= 1) {
        if (c < off) { r0[c] += r0[c + off]; r1[c] += r1[c + off]; }
        __syncthreads();
    }
    if (c == 0) {
        out[(long long)g * 2 + 0] = r0[0] + hb2[0];
        out[(long long)g * 2 + 1] = r1[0] + hb2[1];
    }
}

extern "C" void kernel_launch(void* const* d_in, const int* in_sizes, int n_in,
                              void* d_out, int out_size, void* d_ws, size_t ws_size,
                              hipStream_t stream) {
    const float* x    = (const float*)d_in[0];
    const int*   ei   = (const int*)d_in[1];
    const int*   batch= (const int*)d_in[2];
    const float* W1   = (const float*)d_in[4];
    const float* b1   = (const float*)d_in[5];
    const float* gn1w = (const float*)d_in[6];
    const float* gn1b = (const float*)d_in[7];
    const float* gn1a = (const float*)d_in[8];
    const float* W2   = (const float*)d_in[9];
    const float* b2   = (const float*)d_in[10];
    const float* gn2w = (const float*)d_in[11];
    const float* gn2b = (const float*)d_in[12];
    const float* gn2a = (const float*)d_in[13];
    const float* H1   = (const float*)d_in[14];
    const float* hb1  = (const float*)d_in[15];
    const float* H2   = (const float*)d_in[16];
    const float* hb2  = (const float*)d_in[17];

    int N = in_sizes[0] / 7;
    int E = in_sizes[1] / 2;
    int G = out_size / 2;
    const int* srcI = ei;
    const int* dstI = ei + E;

    // workspace layout
    float* P     = (float*)d_ws;                    // N*128
    float* Q     = P + (size_t)N * HDIM;            // N*128
    float* gsum  = Q + (size_t)N * HDIM;            // G*128
    float* gsq   = gsum + (size_t)G * HDIM;         // G*128
    float* gpool = gsq + (size_t)G * HDIM;          // G*128
    float* gcnt  = gpool + (size_t)G * HDIM;        // G
    float* dinv  = gcnt + G;                        // N
    int* degI    = (int*)(dinv + N);                // N
    int* rowStart= degI + N;                        // N+2
    int* blkSum  = rowStart + (N + 2);              // 512
    int* cursor  = blkSum + 512;                    // N
    int* col     = cursor + N;                      // E

    long long NH = (long long)N * HDIM;
    int gridNH = (int)((NH + 255) / 256);
    int gridN  = (N + 255) / 256;
    int gridE  = (E + 255) / 256;
    int gridNW = (N + 3) / 4;           // wave-per-node kernels
    int gridGH = (G * HDIM + 255) / 256;
    int gridMM = (N + 63) / 64;
    int nblk   = (N + 255) / 256;

    // ---- CSR build ----
    hipMemsetAsync(degI, 0, (size_t)N * 4, stream);
    count_deg_i<<<gridE, 256, 0, stream>>>(dstI, degI, E);
    scan_blk<<<nblk, 256, 0, stream>>>(degI, rowStart, blkSum, N);
    scan_top<<<1, 512, 0, stream>>>(blkSum, nblk);
    finalize_rows<<<gridN, 256, 0, stream>>>(rowStart, degI, blkSum, N);
    make_dinv<<<gridN, 256, 0, stream>>>(degI, dinv, N);
    hipMemsetAsync(cursor, 0, (size_t)N * 4, stream);
    scatter_edges<<<gridE, 256, 0, stream>>>(srcI, dstI, rowStart, cursor, col, E);

    // per-graph node counts
    hipMemsetAsync(gcnt, 0, (size_t)G * 4, stream);
    count_nodes<<<gridN, 256, 0, stream>>>(batch, gcnt, N);

    // ---- block 1 ----
    mm_in<<<gridNH, 256, 0, stream>>>(x, W1, dinv, P, N);
    hipMemsetAsync(gsum, 0, (size_t)G * HDIM * 4, stream);
    hipMemsetAsync(gsq, 0, (size_t)G * HDIM * 4, stream);
    node_agg<<<gridNW, 256, 0, stream>>>(col, rowStart, P, dinv, b1, batch, Q, gsum, gsq, N);
    gstat<<<gridGH, 256, 0, stream>>>(gsum, gsq, gcnt, gn1a, G * HDIM);
    norm_relu<<<gridNH, 256, 0, stream>>>(Q, gsum, gsq, gn1a, gn1w, gn1b, batch, P, N);

    // ---- block 2 ----
    mm_h<<<gridMM, 256, 0, stream>>>(P, W2, dinv, Q, N);
    hipMemsetAsync(gsum, 0, (size_t)G * HDIM * 4, stream);
    hipMemsetAsync(gsq, 0, (size_t)G * HDIM * 4, stream);
    node_agg<<<gridNW, 256, 0, stream>>>(col, rowStart, Q, dinv, b2, batch, P, gsum, gsq, N);
    gstat<<<gridGH, 256, 0, stream>>>(gsum, gsq, gcnt, gn2a, G * HDIM);

    // ---- layer-2 norm + relu + pool fused ----
    hipMemsetAsync(gpool, 0, (size_t)G * HDIM * 4, stream);
    node_norm_pool<<<gridNW, 256, 0, stream>>>(P, gsum, gsq, gn2a, gn2w, gn2b, batch, gpool, N);

    // ---- head ----
    head<<<G, 128, 0, stream>>>(gpool, gcnt, H1, hb1, H2, hb2, (float*)d_out, G);
}

// Round 3
// 832.132 us; speedup vs baseline: 7.0084x; 1.3372x over previous
//
#include <hip/hip_runtime.h>
#include <hip/hip_fp16.h>

#define EPSV 1e-5f
#define HDIM 128

// ---------------- degree count (int) ----------------
__global__ __launch_bounds__(256) void count_deg_i(const int* __restrict__ dst,
                                                   int* __restrict__ deg, int E) {
    int e = blockIdx.x * 256 + threadIdx.x;
    if (e < E) atomicAdd(&deg[dst[e]], 1);
}

// ---------------- 2-level exclusive scan for CSR row starts ----------------
__global__ __launch_bounds__(256) void scan_blk(const int* __restrict__ deg,
                                                int* __restrict__ rowPart,
                                                int* __restrict__ blkSum, int N) {
    __shared__ int tmp[256];
    int tid = threadIdx.x;
    int i = blockIdx.x * 256 + tid;
    int v = (i < N) ? deg[i] : 0;
    tmp[tid] = v;
    __syncthreads();
    for (int off = 1; off < 256; off <<= 1) {
        int t = (tid >= off) ? tmp[tid - off] : 0;
        __syncthreads();
        tmp[tid] += t;
        __syncthreads();
    }
    if (i < N) rowPart[i] = tmp[tid];
    if (tid == 255) blkSum[blockIdx.x] = tmp[255];
}

__global__ __launch_bounds__(512) void scan_top(int* __restrict__ blkSum, int nblk) {
    __shared__ int tmp[512];
    int tid = threadIdx.x;
    int v = (tid < nblk) ? blkSum[tid] : 0;
    tmp[tid] = v;
    __syncthreads();
    for (int off = 1; off < 512; off <<= 1) {
        int t = (tid >= off) ? tmp[tid - off] : 0;
        __syncthreads();
        tmp[tid] += t;
        __syncthreads();
    }
    if (tid < nblk) blkSum[tid] = tmp[tid];
}

__global__ __launch_bounds__(256) void finalize_rows(int* __restrict__ rowStart,
                                                     const int* __restrict__ deg,
                                                     const int* __restrict__ blkSum, int N) {
    int i = blockIdx.x * 256 + threadIdx.x;
    if (i < N) {
        int b = i >> 8;
        int off = b ? blkSum[b - 1] : 0;
        rowStart[i] = rowStart[i] - deg[i] + off;
        if (i == N - 1) rowStart[N] = blkSum[(N + 255) / 256 - 1];
    }
}

__global__ __launch_bounds__(256) void make_dinv(const int* __restrict__ deg,
                                                 float* __restrict__ dinv, int N) {
    int i = blockIdx.x * 256 + threadIdx.x;
    if (i < N) dinv[i] = rsqrtf((float)deg[i] + 1.0f);
}

__global__ __launch_bounds__(256) void scatter_edges(const int* __restrict__ src,
                                                     const int* __restrict__ dst,
                                                     const int* __restrict__ rowStart,
                                                     int* __restrict__ cursor,
                                                     int* __restrict__ col, int E) {
    int e = blockIdx.x * 256 + threadIdx.x;
    if (e < E) {
        int d = dst[e];
        int slot = rowStart[d] + atomicAdd(&cursor[d], 1);
        col[slot] = src[e];
    }
}

// ---------------- count nodes per graph ----------------
__global__ __launch_bounds__(256) void count_nodes(const int* __restrict__ batch,
                                                   float* __restrict__ gcnt, int N) {
    int i = blockIdx.x * 256 + threadIdx.x;
    if (i < N) unsafeAtomicAdd(&gcnt[batch[i]], 1.0f);
}

// ---------------- xs = dinv * x, padded [N][8] ----------------
__global__ __launch_bounds__(256) void prep_xs(const float* __restrict__ x,
                                               const float* __restrict__ dinv,
                                               float* __restrict__ xs, long long total) {
    long long idx = (long long)blockIdx.x * 256 + threadIdx.x;
    if (idx >= total) return;
    int n = (int)(idx >> 3), k = (int)(idx & 7);
    xs[idx] = (k < 7) ? x[(long long)n * 7 + k] * dinv[n] : 0.f;
}

// ---------------- layer-1 aggregation on 8-wide rows (8 threads per node) ----------------
__global__ __launch_bounds__(256) void agg7k(const int* __restrict__ col,
                                             const int* __restrict__ rowStart,
                                             const float* __restrict__ xs,
                                             float* __restrict__ agg, int N) {
    int tid = threadIdx.x;
    int node = blockIdx.x * 32 + (tid >> 3);
    int j = tid & 7;
    if (node >= N) return;
    float acc = xs[(size_t)node * 8 + j];    // self term
    int rs = rowStart[node], re = rowStart[node + 1];
    int e = rs;
    for (; e + 1 < re; e += 2) {
        int s0 = col[e], s1 = col[e + 1];
        acc += xs[(size_t)s0 * 8 + j] + xs[(size_t)s1 * 8 + j];
    }
    if (e < re) acc += xs[(size_t)col[e] * 8 + j];
    agg[(size_t)node * 8 + j] = acc;
}

// ---------------- layer-1 post: A = dinv*(agg@W1)+b1, accumulate stats ----------------
__global__ __launch_bounds__(512) void l1post(const float* __restrict__ agg,
                                              const float* __restrict__ W1,
                                              const float* __restrict__ b1,
                                              const float* __restrict__ dinv,
                                              const int* __restrict__ batch,
                                              float* __restrict__ A,
                                              float* __restrict__ gsum,
                                              float* __restrict__ gsq, int N) {
    __shared__ float w1s[7 * HDIM];
    __shared__ float red_s[4][HDIM], red_q[4][HDIM];
    __shared__ int bsh[4];
    int t = threadIdx.x;
    for (int i = t; i < 7 * HDIM; i += 512) w1s[i] = W1[i];
    int wib = t >> 7, c = t & 127;
    int n = blockIdx.x * 4 + wib;
    __syncthreads();
    bool act = (n < N);
    float v = 0.f;
    int b = -1;
    if (act) {
        b = batch[n];
        const float* ar = agg + (size_t)n * 8;
        float s = 0.f;
#pragma unroll
        for (int k = 0; k < 7; k++) s += ar[k] * w1s[k * HDIM + c];
        v = s * dinv[n] + b1[c];
        A[(size_t)n * HDIM + c] = v;
    }
    if (c == 0) bsh[wib] = act ? b : -1;
    red_s[wib][c] = v;
    red_q[wib][c] = v * v;
    __syncthreads();
    int b0 = bsh[0];
    bool uni = (b0 >= 0) && (bsh[1] == b0) && (bsh[2] == b0) && (bsh[3] == b0);
    if (uni) {
        if (wib == 0) {
            float vs = red_s[0][c] + red_s[1][c] + red_s[2][c] + red_s[3][c];
            float qs = red_q[0][c] + red_q[1][c] + red_q[2][c] + red_q[3][c];
            unsafeAtomicAdd(&gsum[(size_t)b0 * HDIM + c], vs);
            unsafeAtomicAdd(&gsq[(size_t)b0 * HDIM + c], qs);
        }
    } else if (act) {
        unsafeAtomicAdd(&gsum[(size_t)b * HDIM + c], v);
        unsafeAtomicAdd(&gsq[(size_t)b * HDIM + c], v * v);
    }
}

// ---------------- per-(graph,channel): sums -> mean, inv-std ----------------
__global__ __launch_bounds__(256) void gstat(float* __restrict__ gsum,
                                             float* __restrict__ gsq,
                                             const float* __restrict__ gcnt,
                                             const float* __restrict__ alpha, int total) {
    int i = blockIdx.x * 256 + threadIdx.x;
    if (i < total) {
        int g = i >> 7, c = i & 127;
        float cnt = fmaxf(gcnt[g], 1.f);
        float mean = gsum[i] / cnt;
        float m2 = gsq[i] / cnt;
        float a = alpha[c];
        float var = m2 + mean * mean * (a * a - 2.f * a);
        gsum[i] = mean;
        gsq[i] = rsqrtf(fmaxf(var, 0.f) + EPSV);
    }
}

// ---------------- hidden matmul with fused layer-1 norm+relu on load, fp16 out ----------------
// Q = half( dinv * (relu(norm(A)) @ W2) )
__global__ __launch_bounds__(256) void mm_h_fused(const float* __restrict__ A,
                                                  const float* __restrict__ gmean,
                                                  const float* __restrict__ gistd,
                                                  const float* __restrict__ alpha,
                                                  const float* __restrict__ w,
                                                  const float* __restrict__ bb,
                                                  const int* __restrict__ batch,
                                                  const float* __restrict__ W,
                                                  const float* __restrict__ dinv,
                                                  __half* __restrict__ Q, int N) {
    __shared__ float xs[64][65];
    __shared__ __align__(16) float ws[64][HDIM];
    __shared__ float pA[HDIM], pW[HDIM], pB[HDIM];
    int t = threadIdx.x;
    for (int i = t; i < HDIM; i += 256) { pA[i] = alpha[i]; pW[i] = w[i]; pB[i] = bb[i]; }
    int tx = t & 15;
    int ty = t >> 4;
    int n0 = blockIdx.x * 64;
    float acc[4][8];
#pragma unroll
    for (int i = 0; i < 4; i++)
#pragma unroll
        for (int j = 0; j < 8; j++) acc[i][j] = 0.f;

    for (int s = 0; s < 2; ++s) {
        __syncthreads();
        // stage normed+relu'd X half-tile
        for (int i = t; i < 64 * 16; i += 256) {
            int nn = i >> 4;
            int kk = (i & 15) * 4;
            int gn = n0 + nn;
            float4 v = make_float4(0.f, 0.f, 0.f, 0.f);
            if (gn < N) {
                v = *(const float4*)(A + (size_t)gn * HDIM + s * 64 + kk);
                int b = batch[gn];
                int c = s * 64 + kk;
                float4 m = *(const float4*)(gmean + (size_t)b * HDIM + c);
                float4 is = *(const float4*)(gistd + (size_t)b * HDIM + c);
                v.x = fmaxf(pW[c] * (v.x - pA[c] * m.x) * is.x + pB[c], 0.f);
                v.y = fmaxf(pW[c + 1] * (v.y - pA[c + 1] * m.y) * is.y + pB[c + 1], 0.f);
                v.z = fmaxf(pW[c + 2] * (v.z - pA[c + 2] * m.z) * is.z + pB[c + 2], 0.f);
                v.w = fmaxf(pW[c + 3] * (v.w - pA[c + 3] * m.w) * is.w + pB[c + 3], 0.f);
            }
            xs[nn][kk] = v.x; xs[nn][kk + 1] = v.y; xs[nn][kk + 2] = v.z; xs[nn][kk + 3] = v.w;
        }
        // stage W half
        for (int i = t; i < 64 * 32; i += 256) {
            int kk = i >> 5;
            int c = (i & 31) * 4;
            *(float4*)&ws[kk][c] = *(const float4*)(W + (size_t)(s * 64 + kk) * HDIM + c);
        }
        __syncthreads();
#pragma unroll 8
        for (int kk = 0; kk < 64; ++kk) {
            float xv[4];
#pragma unroll
            for (int i = 0; i < 4; i++) xv[i] = xs[ty * 4 + i][kk];
            float4 w0 = *(const float4*)&ws[kk][tx * 4];
            float4 w1 = *(const float4*)&ws[kk][64 + tx * 4];
#pragma unroll
            for (int i = 0; i < 4; i++) {
                acc[i][0] += xv[i] * w0.x; acc[i][1] += xv[i] * w0.y;
                acc[i][2] += xv[i] * w0.z; acc[i][3] += xv[i] * w0.w;
                acc[i][4] += xv[i] * w1.x; acc[i][5] += xv[i] * w1.y;
                acc[i][6] += xv[i] * w1.z; acc[i][7] += xv[i] * w1.w;
            }
        }
    }
#pragma unroll
    for (int i = 0; i < 4; i++) {
        int gn = n0 + ty * 4 + i;
        if (gn >= N) continue;
        float dv = dinv[gn];
        __half2* q0 = (__half2*)(Q + (size_t)gn * HDIM + tx * 4);
        __half2* q1 = (__half2*)(Q + (size_t)gn * HDIM + 64 + tx * 4);
        q0[0] = __floats2half2_rn(acc[i][0] * dv, acc[i][1] * dv);
        q0[1] = __floats2half2_rn(acc[i][2] * dv, acc[i][3] * dv);
        q1[0] = __floats2half2_rn(acc[i][4] * dv, acc[i][5] * dv);
        q1[1] = __floats2half2_rn(acc[i][6] * dv, acc[i][7] * dv);
    }
}

// ---------------- layer-2 CSR gather on fp16 rows + bias + stats (wave per node) ----------------
__global__ __launch_bounds__(256) void node_agg2(const int* __restrict__ col,
                                                 const int* __restrict__ rowStart,
                                                 const __half* __restrict__ Q,
                                                 const float* __restrict__ dinv,
                                                 const float* __restrict__ bias,
                                                 const int* __restrict__ batch,
                                                 float* __restrict__ Aout,
                                                 float* __restrict__ gsum,
                                                 float* __restrict__ gsq, int N) {
    __shared__ float sv[4][HDIM];
    __shared__ float sq[4][HDIM];
    __shared__ int bsh[4];
    int wib = threadIdx.x >> 6, lane = threadIdx.x & 63;
    int c = lane * 2;
    int n = blockIdx.x * 4 + wib;
    bool active = (n < N);
    float2 acc = make_float2(0.f, 0.f);
    int b = -1;
    if (active) {
        b = batch[n];
        acc = __half22float2(*(const __half2*)(Q + (size_t)n * HDIM + c));  // self
        int rs = rowStart[n], re = rowStart[n + 1];
        int j = rs;
        for (; j + 1 < re; j += 2) {
            int s0 = col[j], s1 = col[j + 1];
            float2 t0 = __half22float2(*(const __half2*)(Q + (size_t)s0 * HDIM + c));
            float2 t1 = __half22float2(*(const __half2*)(Q + (size_t)s1 * HDIM + c));
            acc.x += t0.x + t1.x;
            acc.y += t0.y + t1.y;
        }
        if (j < re) {
            float2 t0 = __half22float2(*(const __half2*)(Q + (size_t)col[j] * HDIM + c));
            acc.x += t0.x;
            acc.y += t0.y;
        }
        float dv = dinv[n];
        acc.x = acc.x * dv + bias[c];
        acc.y = acc.y * dv + bias[c + 1];
        *(float2*)(Aout + (size_t)n * HDIM + c) = acc;
    }
    if (lane == 0) bsh[wib] = active ? b : -1;
    sv[wib][c] = acc.x;         sv[wib][c + 1] = acc.y;
    sq[wib][c] = acc.x * acc.x; sq[wib][c + 1] = acc.y * acc.y;
    __syncthreads();
    int b0 = bsh[0];
    bool uni = (b0 >= 0) && (bsh[1] == b0) && (bsh[2] == b0) && (bsh[3] == b0);
    if (uni) {
        if (wib == 0) {
            float vx = sv[0][c] + sv[1][c] + sv[2][c] + sv[3][c];
            float vy = sv[0][c + 1] + sv[1][c + 1] + sv[2][c + 1] + sv[3][c + 1];
            float qx = sq[0][c] + sq[1][c] + sq[2][c] + sq[3][c];
            float qy = sq[0][c + 1] + sq[1][c + 1] + sq[2][c + 1] + sq[3][c + 1];
            unsafeAtomicAdd(&gsum[(size_t)b0 * HDIM + c], vx);
            unsafeAtomicAdd(&gsum[(size_t)b0 * HDIM + c + 1], vy);
            unsafeAtomicAdd(&gsq[(size_t)b0 * HDIM + c], qx);
            unsafeAtomicAdd(&gsq[(size_t)b0 * HDIM + c + 1], qy);
        }
    } else if (active) {
        unsafeAtomicAdd(&gsum[(size_t)b * HDIM + c], acc.x);
        unsafeAtomicAdd(&gsum[(size_t)b * HDIM + c + 1], acc.y);
        unsafeAtomicAdd(&gsq[(size_t)b * HDIM + c], acc.x * acc.x);
        unsafeAtomicAdd(&gsq[(size_t)b * HDIM + c + 1], acc.y * acc.y);
    }
}

// ---------------- layer-2 normalize+relu fused with pool atomics (wave per node) ----------------
__global__ __launch_bounds__(256) void node_norm_pool(const float* __restrict__ X,
                                                      const float* __restrict__ gmean,
                                                      const float* __restrict__ gistd,
                                                      const float* __restrict__ alpha,
                                                      const float* __restrict__ w,
                                                      const float* __restrict__ bb,
                                                      const int* __restrict__ batch,
                                                      float* __restrict__ gpool, int N) {
    __shared__ float sv[4][HDIM];
    __shared__ int bsh[4];
    int wib = threadIdx.x >> 6, lane = threadIdx.x & 63;
    int c = lane * 2;
    int n = blockIdx.x * 4 + wib;
    bool active = (n < N);
    float2 y = make_float2(0.f, 0.f);
    int b = -1;
    if (active) {
        b = batch[n];
        float2 v = *(const float2*)(X + (size_t)n * HDIM + c);
        float2 m = *(const float2*)(gmean + (size_t)b * HDIM + c);
        float2 is = *(const float2*)(gistd + (size_t)b * HDIM + c);
        y.x = fmaxf(w[c] * (v.x - alpha[c] * m.x) * is.x + bb[c], 0.f);
        y.y = fmaxf(w[c + 1] * (v.y - alpha[c + 1] * m.y) * is.y + bb[c + 1], 0.f);
    }
    if (lane == 0) bsh[wib] = active ? b : -1;
    sv[wib][c] = y.x; sv[wib][c + 1] = y.y;
    __syncthreads();
    int b0 = bsh[0];
    bool uni = (b0 >= 0) && (bsh[1] == b0) && (bsh[2] == b0) && (bsh[3] == b0);
    if (uni) {
        if (wib == 0) {
            float vx = sv[0][c] + sv[1][c] + sv[2][c] + sv[3][c];
            float vy = sv[0][c + 1] + sv[1][c + 1] + sv[2][c + 1] + sv[3][c + 1];
            unsafeAtomicAdd(&gpool[(size_t)b0 * HDIM + c], vx);
            unsafeAtomicAdd(&gpool[(size_t)b0 * HDIM + c + 1], vy);
        }
    } else if (active) {
        unsafeAtomicAdd(&gpool[(size_t)b * HDIM + c], y.x);
        unsafeAtomicAdd(&gpool[(size_t)b * HDIM + c + 1], y.y);
    }
}

// ---------------- head ----------------
__global__ __launch_bounds__(128) void head(const float* __restrict__ gpool,
                                            const float* __restrict__ gcnt,
                                            const float* __restrict__ H1,
                                            const float* __restrict__ hb1,
                                            const float* __restrict__ H2,
                                            const float* __restrict__ hb2,
                                            float* __restrict__ out, int G) {
    __shared__ float gv[HDIM];
    __shared__ float tv[HDIM];
    __shared__ float r0[HDIM], r1[HDIM];
    int g = blockIdx.x;
    int c = threadIdx.x;
    float cnt = fmaxf(gcnt[g], 1.0f);
    gv[c] = gpool[(long long)g * HDIM + c] / cnt;
    __syncthreads();
    float s = hb1[c];
    for (int k = 0; k < HDIM; k++) s += gv[k] * H1[k * HDIM + c];
    tv[c] = fmaxf(s, 0.f);
    __syncthreads();
    r0[c] = tv[c] * H2[c * 2 + 0];
    r1[c] = tv[c] * H2[c * 2 + 1];
    __syncthreads();
    for (int off = 64; off > 0; off >>= 1) {
        if (c < off) { r0[c] += r0[c + off]; r1[c] += r1[c + off]; }
        __syncthreads();
    }
    if (c == 0) {
        out[(long long)g * 2 + 0] = r0[0] + hb2[0];
        out[(long long)g * 2 + 1] = r1[0] + hb2[1];
    }
}

extern "C" void kernel_launch(void* const* d_in, const int* in_sizes, int n_in,
                              void* d_out, int out_size, void* d_ws, size_t ws_size,
                              hipStream_t stream) {
    const float* x    = (const float*)d_in[0];
    const int*   ei   = (const int*)d_in[1];
    const int*   batch= (const int*)d_in[2];
    const float* W1   = (const float*)d_in[4];
    const float* b1   = (const float*)d_in[5];
    const float* gn1w = (const float*)d_in[6];
    const float* gn1b = (const float*)d_in[7];
    const float* gn1a = (const float*)d_in[8];
    const float* W2   = (const float*)d_in[9];
    const float* b2   = (const float*)d_in[10];
    const float* gn2w = (const float*)d_in[11];
    const float* gn2b = (const float*)d_in[12];
    const float* gn2a = (const float*)d_in[13];
    const float* H1   = (const float*)d_in[14];
    const float* hb1  = (const float*)d_in[15];
    const float* H2   = (const float*)d_in[16];
    const float* hb2  = (const float*)d_in[17];

    int N = in_sizes[0] / 7;
    int E = in_sizes[1] / 2;
    int G = out_size / 2;
    const int* srcI = ei;
    const int* dstI = ei + E;

    // workspace layout (~99 MB)
    float*  A    = (float*)d_ws;                    // N*128 fp32 (pre-norm, both layers)
    __half* Q16  = (__half*)(A + (size_t)N * HDIM); // N*128 half
    float*  xs   = (float*)(Q16 + (size_t)N * HDIM);// N*8
    float*  agg  = xs + (size_t)N * 8;              // N*8
    float*  gsum = agg + (size_t)N * 8;             // G*128
    float*  gsq  = gsum + (size_t)G * HDIM;         // G*128
    float*  gpool= gsq + (size_t)G * HDIM;          // G*128
    float*  gcnt = gpool + (size_t)G * HDIM;        // G
    float*  dinv = gcnt + G;                        // N
    int* degI    = (int*)(dinv + N);                // N
    int* rowStart= degI + N;                        // N+2
    int* blkSum  = rowStart + (N + 2);              // 512
    int* cursor  = blkSum + 512;                    // N
    int* col     = cursor + N;                      // E

    int gridN  = (N + 255) / 256;
    int gridE  = (E + 255) / 256;
    int gridNW = (N + 3) / 4;
    int gridGH = (G * HDIM + 255) / 256;
    int gridMM = (N + 63) / 64;
    int nblk   = (N + 255) / 256;

    // ---- CSR build ----
    hipMemsetAsync(degI, 0, (size_t)N * 4, stream);
    count_deg_i<<<gridE, 256, 0, stream>>>(dstI, degI, E);
    scan_blk<<<nblk, 256, 0, stream>>>(degI, rowStart, blkSum, N);
    scan_top<<<1, 512, 0, stream>>>(blkSum, nblk);
    finalize_rows<<<gridN, 256, 0, stream>>>(rowStart, degI, blkSum, N);
    make_dinv<<<gridN, 256, 0, stream>>>(degI, dinv, N);
    hipMemsetAsync(cursor, 0, (size_t)N * 4, stream);
    scatter_edges<<<gridE, 256, 0, stream>>>(srcI, dstI, rowStart, cursor, col, E);

    // per-graph node counts
    hipMemsetAsync(gcnt, 0, (size_t)G * 4, stream);
    count_nodes<<<gridN, 256, 0, stream>>>(batch, gcnt, N);

    // ---- block 1 (rank-7 aggregation) ----
    long long nx8 = (long long)N * 8;
    prep_xs<<<(int)((nx8 + 255) / 256), 256, 0, stream>>>(x, dinv, xs, nx8);
    agg7k<<<(N + 31) / 32, 256, 0, stream>>>(col, rowStart, xs, agg, N);
    hipMemsetAsync(gsum, 0, (size_t)G * HDIM * 4, stream);
    hipMemsetAsync(gsq, 0, (size_t)G * HDIM * 4, stream);
    l1post<<<gridNW, 512, 0, stream>>>(agg, W1, b1, dinv, batch, A, gsum, gsq, N);
    gstat<<<gridGH, 256, 0, stream>>>(gsum, gsq, gcnt, gn1a, G * HDIM);

    // ---- mm_h with fused layer-1 norm+relu, fp16 output ----
    mm_h_fused<<<gridMM, 256, 0, stream>>>(A, gsum, gsq, gn1a, gn1w, gn1b, batch,
                                           W2, dinv, Q16, N);

    // ---- block 2 (fp16 gather) ----
    hipMemsetAsync(gsum, 0, (size_t)G * HDIM * 4, stream);
    hipMemsetAsync(gsq, 0, (size_t)G * HDIM * 4, stream);
    node_agg2<<<gridNW, 256, 0, stream>>>(col, rowStart, Q16, dinv, b2, batch, A, gsum, gsq, N);
    gstat<<<gridGH, 256, 0, stream>>>(gsum, gsq, gcnt, gn2a, G * HDIM);

    // ---- layer-2 norm + relu + pool fused ----
    hipMemsetAsync(gpool, 0, (size_t)G * HDIM * 4, stream);
    node_norm_pool<<<gridNW, 256, 0, stream>>>(A, gsum, gsq, gn2a, gn2w, gn2b, batch, gpool, N);

    // ---- head ----
    head<<<G, 128, 0, stream>>>(gpool, gcnt, H1, hb1, H2, hb2, (float*)d_out, G);
}

// Round 4
// 562.329 us; speedup vs baseline: 10.3709x; 1.4798x over previous
//
#include <hip/hip_runtime.h>
#include <hip/hip_fp16.h>

#define EPSV 1e-5f
#define HDIM 128
#define BKT_SHIFT 9
#define BKT_SIZE 512
#define CHK 8192

// ================= CSR build: bucketed counting sort =================

// per-chunk histogram over dst buckets
__global__ __launch_bounds__(256) void hist_pass(const int* __restrict__ dst,
                                                 int* __restrict__ histG, int E, int NB) {
    __shared__ int h[BKT_SIZE];
    int t = threadIdx.x;
    for (int i = t; i < NB; i += 256) h[i] = 0;
    __syncthreads();
    int base = blockIdx.x * CHK;
    int end = min(base + CHK, E);
    for (int e = base + t; e < end; e += 256) atomicAdd(&h[dst[e] >> BKT_SHIFT], 1);
    __syncthreads();
    for (int i = t; i < NB; i += 256) histG[(size_t)blockIdx.x * NB + i] = h[i];
}

// per-bucket exclusive scan over chunks; tot[b] = bucket total
__global__ __launch_bounds__(512) void scan_chunks(int* __restrict__ histG,
                                                   int* __restrict__ tot,
                                                   int NCHUNK, int NB) {
    __shared__ int tmp[512];
    int b = blockIdx.x, t = threadIdx.x;
    int v = (t < NCHUNK) ? histG[(size_t)t * NB + b] : 0;
    tmp[t] = v;
    __syncthreads();
    for (int off = 1; off < 512; off <<= 1) {
        int x = (t >= off) ? tmp[t - off] : 0;
        __syncthreads();
        tmp[t] += x;
        __syncthreads();
    }
    if (t < NCHUNK) histG[(size_t)t * NB + b] = tmp[t] - v;   // exclusive within bucket
    if (t == 511) tot[b] = tmp[511];
}

// exclusive scan over buckets -> bucketBase; also writes rowStart[N]=E sentinel
__global__ __launch_bounds__(512) void scan_tot_k(const int* __restrict__ tot,
                                                  int* __restrict__ bucketBase,
                                                  int* __restrict__ rowStart,
                                                  int NB, int N, int E) {
    __shared__ int tmp[512];
    int t = threadIdx.x;
    int v = (t < NB) ? tot[t] : 0;
    tmp[t] = v;
    __syncthreads();
    for (int off = 1; off < 512; off <<= 1) {
        int x = (t >= off) ? tmp[t - off] : 0;
        __syncthreads();
        tmp[t] += x;
        __syncthreads();
    }
    if (t < NB) bucketBase[t] = tmp[t] - v;
    if (t == NB - 1) {
        bucketBase[NB] = tmp[t];
        rowStart[N] = E;
    }
}

// chunkOff[c][b] += bucketBase[b]
__global__ __launch_bounds__(256) void add_base(int* __restrict__ histG,
                                                const int* __restrict__ bucketBase,
                                                int total, int NB) {
    int i = blockIdx.x * 256 + threadIdx.x;
    if (i < total) histG[i] += bucketBase[i % NB];
}

// scatter edges into bucket-grouped array, packed as src | local_dst<<23
__global__ __launch_bounds__(256) void scatter_bkt(const int* __restrict__ src,
                                                   const int* __restrict__ dst,
                                                   const int* __restrict__ chunkOff,
                                                   unsigned int* __restrict__ EP,
                                                   int E, int NB) {
    __shared__ int cur[BKT_SIZE];
    int t = threadIdx.x, c = blockIdx.x;
    for (int i = t; i < NB; i += 256) cur[i] = chunkOff[(size_t)c * NB + i];
    __syncthreads();
    int base = c * CHK, end = min(base + CHK, E);
    for (int e = base + t; e < end; e += 256) {
        int d = dst[e];
        int b = d >> BKT_SHIFT;
        int pos = atomicAdd(&cur[b], 1);
        EP[pos] = (unsigned int)src[e] | ((unsigned int)(d & (BKT_SIZE - 1)) << 23);
    }
}

// per-bucket exact counting sort -> rowStart, dinv, col
__global__ __launch_bounds__(512) void bucket_csr(const unsigned int* __restrict__ EP,
                                                  const int* __restrict__ bucketBase,
                                                  int* __restrict__ rowStart,
                                                  float* __restrict__ dinv,
                                                  int* __restrict__ col, int N) {
    __shared__ int cnt[BKT_SIZE];
    __shared__ int tmp[BKT_SIZE];
    int b = blockIdx.x, t = threadIdx.x;
    int ebase = bucketBase[b], eend = bucketBase[b + 1];
    cnt[t] = 0;
    __syncthreads();
    for (int e = ebase + t; e < eend; e += 512)
        atomicAdd(&cnt[(EP[e] >> 23) & 511], 1);
    __syncthreads();
    int v = cnt[t];
    tmp[t] = v;
    __syncthreads();
    for (int off = 1; off < 512; off <<= 1) {
        int x = (t >= off) ? tmp[t - off] : 0;
        __syncthreads();
        tmp[t] += x;
        __syncthreads();
    }
    int excl = tmp[t] - v;
    int n = (b << BKT_SHIFT) + t;
    if (n < N) {
        rowStart[n] = ebase + excl;
        dinv[n] = rsqrtf((float)v + 1.0f);
    }
    __syncthreads();
    cnt[t] = ebase + excl;   // reuse as cursor
    __syncthreads();
    for (int e = ebase + t; e < eend; e += 512) {
        unsigned int p = EP[e];
        int ld = (p >> 23) & 511;
        int pos = atomicAdd(&cnt[ld], 1);
        col[pos] = (int)(p & 0x7FFFFFu);
    }
}

// ---------------- count nodes per graph ----------------
__global__ __launch_bounds__(256) void count_nodes(const int* __restrict__ batch,
                                                   float* __restrict__ gcnt, int N) {
    int i = blockIdx.x * 256 + threadIdx.x;
    if (i < N) unsafeAtomicAdd(&gcnt[batch[i]], 1.0f);
}

// ---------------- xs = dinv * x, padded [N][8] ----------------
__global__ __launch_bounds__(256) void prep_xs(const float* __restrict__ x,
                                               const float* __restrict__ dinv,
                                               float* __restrict__ xs, long long total) {
    long long idx = (long long)blockIdx.x * 256 + threadIdx.x;
    if (idx >= total) return;
    int n = (int)(idx >> 3), k = (int)(idx & 7);
    xs[idx] = (k < 7) ? x[(long long)n * 7 + k] * dinv[n] : 0.f;
}

// ---------------- layer-1 aggregation on 8-wide rows (8 threads per node) ----------------
__global__ __launch_bounds__(256) void agg7k(const int* __restrict__ col,
                                             const int* __restrict__ rowStart,
                                             const float* __restrict__ xs,
                                             float* __restrict__ agg, int N) {
    int tid = threadIdx.x;
    int node = blockIdx.x * 32 + (tid >> 3);
    int j = tid & 7;
    if (node >= N) return;
    float acc = xs[(size_t)node * 8 + j];    // self term
    int rs = rowStart[node], re = rowStart[node + 1];
    int e = rs;
    for (; e + 1 < re; e += 2) {
        int s0 = col[e], s1 = col[e + 1];
        acc += xs[(size_t)s0 * 8 + j] + xs[(size_t)s1 * 8 + j];
    }
    if (e < re) acc += xs[(size_t)col[e] * 8 + j];
    agg[(size_t)node * 8 + j] = acc;
}

// ---------------- layer-1 post: A = dinv*(agg@W1)+b1, accumulate stats ----------------
__global__ __launch_bounds__(512) void l1post(const float* __restrict__ agg,
                                              const float* __restrict__ W1,
                                              const float* __restrict__ b1,
                                              const float* __restrict__ dinv,
                                              const int* __restrict__ batch,
                                              float* __restrict__ A,
                                              float* __restrict__ gsum,
                                              float* __restrict__ gsq, int N) {
    __shared__ float w1s[7 * HDIM];
    __shared__ float red_s[4][HDIM], red_q[4][HDIM];
    __shared__ int bsh[4];
    int t = threadIdx.x;
    for (int i = t; i < 7 * HDIM; i += 512) w1s[i] = W1[i];
    int wib = t >> 7, c = t & 127;
    int n = blockIdx.x * 4 + wib;
    __syncthreads();
    bool act = (n < N);
    float v = 0.f;
    int b = -1;
    if (act) {
        b = batch[n];
        const float* ar = agg + (size_t)n * 8;
        float s = 0.f;
#pragma unroll
        for (int k = 0; k < 7; k++) s += ar[k] * w1s[k * HDIM + c];
        v = s * dinv[n] + b1[c];
        A[(size_t)n * HDIM + c] = v;
    }
    if (c == 0) bsh[wib] = act ? b : -1;
    red_s[wib][c] = v;
    red_q[wib][c] = v * v;
    __syncthreads();
    int b0 = bsh[0];
    bool uni = (b0 >= 0) && (bsh[1] == b0) && (bsh[2] == b0) && (bsh[3] == b0);
    if (uni) {
        if (wib == 0) {
            float vs = red_s[0][c] + red_s[1][c] + red_s[2][c] + red_s[3][c];
            float qs = red_q[0][c] + red_q[1][c] + red_q[2][c] + red_q[3][c];
            unsafeAtomicAdd(&gsum[(size_t)b0 * HDIM + c], vs);
            unsafeAtomicAdd(&gsq[(size_t)b0 * HDIM + c], qs);
        }
    } else if (act) {
        unsafeAtomicAdd(&gsum[(size_t)b * HDIM + c], v);
        unsafeAtomicAdd(&gsq[(size_t)b * HDIM + c], v * v);
    }
}

// ---------------- per-(graph,channel): sums -> mean, inv-std ----------------
__global__ __launch_bounds__(256) void gstat(float* __restrict__ gsum,
                                             float* __restrict__ gsq,
                                             const float* __restrict__ gcnt,
                                             const float* __restrict__ alpha, int total) {
    int i = blockIdx.x * 256 + threadIdx.x;
    if (i < total) {
        int g = i >> 7, c = i & 127;
        float cnt = fmaxf(gcnt[g], 1.f);
        float mean = gsum[i] / cnt;
        float m2 = gsq[i] / cnt;
        float a = alpha[c];
        float var = m2 + mean * mean * (a * a - 2.f * a);
        gsum[i] = mean;
        gsq[i] = rsqrtf(fmaxf(var, 0.f) + EPSV);
    }
}

// ---------------- hidden matmul with fused layer-1 norm+relu on load, fp16 out ----------------
__global__ __launch_bounds__(256) void mm_h_fused(const float* __restrict__ A,
                                                  const float* __restrict__ gmean,
                                                  const float* __restrict__ gistd,
                                                  const float* __restrict__ alpha,
                                                  const float* __restrict__ w,
                                                  const float* __restrict__ bb,
                                                  const int* __restrict__ batch,
                                                  const float* __restrict__ W,
                                                  const float* __restrict__ dinv,
                                                  __half* __restrict__ Q, int N) {
    __shared__ float xs[64][65];
    __shared__ __align__(16) float ws[64][HDIM];
    __shared__ float pA[HDIM], pW[HDIM], pB[HDIM];
    int t = threadIdx.x;
    for (int i = t; i < HDIM; i += 256) { pA[i] = alpha[i]; pW[i] = w[i]; pB[i] = bb[i]; }
    int tx = t & 15;
    int ty = t >> 4;
    int n0 = blockIdx.x * 64;
    float acc[4][8];
#pragma unroll
    for (int i = 0; i < 4; i++)
#pragma unroll
        for (int j = 0; j < 8; j++) acc[i][j] = 0.f;

    for (int s = 0; s < 2; ++s) {
        __syncthreads();
        for (int i = t; i < 64 * 16; i += 256) {
            int nn = i >> 4;
            int kk = (i & 15) * 4;
            int gn = n0 + nn;
            float4 v = make_float4(0.f, 0.f, 0.f, 0.f);
            if (gn < N) {
                v = *(const float4*)(A + (size_t)gn * HDIM + s * 64 + kk);
                int b = batch[gn];
                int c = s * 64 + kk;
                float4 m = *(const float4*)(gmean + (size_t)b * HDIM + c);
                float4 is = *(const float4*)(gistd + (size_t)b * HDIM + c);
                v.x = fmaxf(pW[c] * (v.x - pA[c] * m.x) * is.x + pB[c], 0.f);
                v.y = fmaxf(pW[c + 1] * (v.y - pA[c + 1] * m.y) * is.y + pB[c + 1], 0.f);
                v.z = fmaxf(pW[c + 2] * (v.z - pA[c + 2] * m.z) * is.z + pB[c + 2], 0.f);
                v.w = fmaxf(pW[c + 3] * (v.w - pA[c + 3] * m.w) * is.w + pB[c + 3], 0.f);
            }
            xs[nn][kk] = v.x; xs[nn][kk + 1] = v.y; xs[nn][kk + 2] = v.z; xs[nn][kk + 3] = v.w;
        }
        for (int i = t; i < 64 * 32; i += 256) {
            int kk = i >> 5;
            int c = (i & 31) * 4;
            *(float4*)&ws[kk][c] = *(const float4*)(W + (size_t)(s * 64 + kk) * HDIM + c);
        }
        __syncthreads();
#pragma unroll 8
        for (int kk = 0; kk < 64; ++kk) {
            float xv[4];
#pragma unroll
            for (int i = 0; i < 4; i++) xv[i] = xs[ty * 4 + i][kk];
            float4 w0 = *(const float4*)&ws[kk][tx * 4];
            float4 w1 = *(const float4*)&ws[kk][64 + tx * 4];
#pragma unroll
            for (int i = 0; i < 4; i++) {
                acc[i][0] += xv[i] * w0.x; acc[i][1] += xv[i] * w0.y;
                acc[i][2] += xv[i] * w0.z; acc[i][3] += xv[i] * w0.w;
                acc[i][4] += xv[i] * w1.x; acc[i][5] += xv[i] * w1.y;
                acc[i][6] += xv[i] * w1.z; acc[i][7] += xv[i] * w1.w;
            }
        }
    }
#pragma unroll
    for (int i = 0; i < 4; i++) {
        int gn = n0 + ty * 4 + i;
        if (gn >= N) continue;
        float dv = dinv[gn];
        __half2* q0 = (__half2*)(Q + (size_t)gn * HDIM + tx * 4);
        __half2* q1 = (__half2*)(Q + (size_t)gn * HDIM + 64 + tx * 4);
        q0[0] = __floats2half2_rn(acc[i][0] * dv, acc[i][1] * dv);
        q0[1] = __floats2half2_rn(acc[i][2] * dv, acc[i][3] * dv);
        q1[0] = __floats2half2_rn(acc[i][4] * dv, acc[i][5] * dv);
        q1[1] = __floats2half2_rn(acc[i][6] * dv, acc[i][7] * dv);
    }
}

// ---------------- layer-2 CSR gather on fp16 rows + bias + stats (wave per node) ----------------
__global__ __launch_bounds__(256) void node_agg2(const int* __restrict__ col,
                                                 const int* __restrict__ rowStart,
                                                 const __half* __restrict__ Q,
                                                 const float* __restrict__ dinv,
                                                 const float* __restrict__ bias,
                                                 const int* __restrict__ batch,
                                                 float* __restrict__ Aout,
                                                 float* __restrict__ gsum,
                                                 float* __restrict__ gsq, int N) {
    __shared__ float sv[4][HDIM];
    __shared__ float sq[4][HDIM];
    __shared__ int bsh[4];
    int wib = threadIdx.x >> 6, lane = threadIdx.x & 63;
    int c = lane * 2;
    int n = blockIdx.x * 4 + wib;
    bool active = (n < N);
    float2 acc = make_float2(0.f, 0.f);
    int b = -1;
    if (active) {
        b = batch[n];
        acc = __half22float2(*(const __half2*)(Q + (size_t)n * HDIM + c));  // self
        int rs = rowStart[n], re = rowStart[n + 1];
        int j = rs;
        for (; j + 1 < re; j += 2) {
            int s0 = col[j], s1 = col[j + 1];
            float2 t0 = __half22float2(*(const __half2*)(Q + (size_t)s0 * HDIM + c));
            float2 t1 = __half22float2(*(const __half2*)(Q + (size_t)s1 * HDIM + c));
            acc.x += t0.x + t1.x;
            acc.y += t0.y + t1.y;
        }
        if (j < re) {
            float2 t0 = __half22float2(*(const __half2*)(Q + (size_t)col[j] * HDIM + c));
            acc.x += t0.x;
            acc.y += t0.y;
        }
        float dv = dinv[n];
        acc.x = acc.x * dv + bias[c];
        acc.y = acc.y * dv + bias[c + 1];
        *(float2*)(Aout + (size_t)n * HDIM + c) = acc;
    }
    if (lane == 0) bsh[wib] = active ? b : -1;
    sv[wib][c] = acc.x;         sv[wib][c + 1] = acc.y;
    sq[wib][c] = acc.x * acc.x; sq[wib][c + 1] = acc.y * acc.y;
    __syncthreads();
    int b0 = bsh[0];
    bool uni = (b0 >= 0) && (bsh[1] == b0) && (bsh[2] == b0) && (bsh[3] == b0);
    if (uni) {
        if (wib == 0) {
            float vx = sv[0][c] + sv[1][c] + sv[2][c] + sv[3][c];
            float vy = sv[0][c + 1] + sv[1][c + 1] + sv[2][c + 1] + sv[3][c + 1];
            float qx = sq[0][c] + sq[1][c] + sq[2][c] + sq[3][c];
            float qy = sq[0][c + 1] + sq[1][c + 1] + sq[2][c + 1] + sq[3][c + 1];
            unsafeAtomicAdd(&gsum[(size_t)b0 * HDIM + c], vx);
            unsafeAtomicAdd(&gsum[(size_t)b0 * HDIM + c + 1], vy);
            unsafeAtomicAdd(&gsq[(size_t)b0 * HDIM + c], qx);
            unsafeAtomicAdd(&gsq[(size_t)b0 * HDIM + c + 1], qy);
        }
    } else if (active) {
        unsafeAtomicAdd(&gsum[(size_t)b * HDIM + c], acc.x);
        unsafeAtomicAdd(&gsum[(size_t)b * HDIM + c + 1], acc.y);
        unsafeAtomicAdd(&gsq[(size_t)b * HDIM + c], acc.x * acc.x);
        unsafeAtomicAdd(&gsq[(size_t)b * HDIM + c + 1], acc.y * acc.y);
    }
}

// ---------------- layer-2 normalize+relu fused with pool atomics (wave per node) ----------------
__global__ __launch_bounds__(256) void node_norm_pool(const float* __restrict__ X,
                                                      const float* __restrict__ gmean,
                                                      const float* __restrict__ gistd,
                                                      const float* __restrict__ alpha,
                                                      const float* __restrict__ w,
                                                      const float* __restrict__ bb,
                                                      const int* __restrict__ batch,
                                                      float* __restrict__ gpool, int N) {
    __shared__ float sv[4][HDIM];
    __shared__ int bsh[4];
    int wib = threadIdx.x >> 6, lane = threadIdx.x & 63;
    int c = lane * 2;
    int n = blockIdx.x * 4 + wib;
    bool active = (n < N);
    float2 y = make_float2(0.f, 0.f);
    int b = -1;
    if (active) {
        b = batch[n];
        float2 v = *(const float2*)(X + (size_t)n * HDIM + c);
        float2 m = *(const float2*)(gmean + (size_t)b * HDIM + c);
        float2 is = *(const float2*)(gistd + (size_t)b * HDIM + c);
        y.x = fmaxf(w[c] * (v.x - alpha[c] * m.x) * is.x + bb[c], 0.f);
        y.y = fmaxf(w[c + 1] * (v.y - alpha[c + 1] * m.y) * is.y + bb[c + 1], 0.f);
    }
    if (lane == 0) bsh[wib] = active ? b : -1;
    sv[wib][c] = y.x; sv[wib][c + 1] = y.y;
    __syncthreads();
    int b0 = bsh[0];
    bool uni = (b0 >= 0) && (bsh[1] == b0) && (bsh[2] == b0) && (bsh[3] == b0);
    if (uni) {
        if (wib == 0) {
            float vx = sv[0][c] + sv[1][c] + sv[2][c] + sv[3][c];
            float vy = sv[0][c + 1] + sv[1][c + 1] + sv[2][c + 1] + sv[3][c + 1];
            unsafeAtomicAdd(&gpool[(size_t)b0 * HDIM + c], vx);
            unsafeAtomicAdd(&gpool[(size_t)b0 * HDIM + c + 1], vy);
        }
    } else if (active) {
        unsafeAtomicAdd(&gpool[(size_t)b * HDIM + c], y.x);
        unsafeAtomicAdd(&gpool[(size_t)b * HDIM + c + 1], y.y);
    }
}

// ---------------- head ----------------
__global__ __launch_bounds__(128) void head(const float* __restrict__ gpool,
                                            const float* __restrict__ gcnt,
                                            const float* __restrict__ H1,
                                            const float* __restrict__ hb1,
                                            const float* __restrict__ H2,
                                            const float* __restrict__ hb2,
                                            float* __restrict__ out, int G) {
    __shared__ float gv[HDIM];
    __shared__ float tv[HDIM];
    __shared__ float r0[HDIM], r1[HDIM];
    int g = blockIdx.x;
    int c = threadIdx.x;
    float cnt = fmaxf(gcnt[g], 1.0f);
    gv[c] = gpool[(long long)g * HDIM + c] / cnt;
    __syncthreads();
    float s = hb1[c];
    for (int k = 0; k < HDIM; k++) s += gv[k] * H1[k * HDIM + c];
    tv[c] = fmaxf(s, 0.f);
    __syncthreads();
    r0[c] = tv[c] * H2[c * 2 + 0];
    r1[c] = tv[c] * H2[c * 2 + 1];
    __syncthreads();
    for (int off = 64; off > 0; off >>= 1) {
        if (c < off) { r0[c] += r0[c + off]; r1[c] += r1[c + off]; }
        __syncthreads();
    }
    if (c == 0) {
        out[(long long)g * 2 + 0] = r0[0] + hb2[0];
        out[(long long)g * 2 + 1] = r1[0] + hb2[1];
    }
}

extern "C" void kernel_launch(void* const* d_in, const int* in_sizes, int n_in,
                              void* d_out, int out_size, void* d_ws, size_t ws_size,
                              hipStream_t stream) {
    const float* x    = (const float*)d_in[0];
    const int*   ei   = (const int*)d_in[1];
    const int*   batch= (const int*)d_in[2];
    const float* W1   = (const float*)d_in[4];
    const float* b1   = (const float*)d_in[5];
    const float* gn1w = (const float*)d_in[6];
    const float* gn1b = (const float*)d_in[7];
    const float* gn1a = (const float*)d_in[8];
    const float* W2   = (const float*)d_in[9];
    const float* b2   = (const float*)d_in[10];
    const float* gn2w = (const float*)d_in[11];
    const float* gn2b = (const float*)d_in[12];
    const float* gn2a = (const float*)d_in[13];
    const float* H1   = (const float*)d_in[14];
    const float* hb1  = (const float*)d_in[15];
    const float* H2   = (const float*)d_in[16];
    const float* hb2  = (const float*)d_in[17];

    int N = in_sizes[0] / 7;
    int E = in_sizes[1] / 2;
    int G = out_size / 2;
    const int* srcI = ei;
    const int* dstI = ei + E;

    int NB = (N + BKT_SIZE - 1) >> BKT_SHIFT;      // 196 buckets
    int NCHUNK = (E + CHK - 1) / CHK;              // 391 chunks

    // workspace layout (~112 MB)
    float*  A    = (float*)d_ws;                    // N*128 fp32
    __half* Q16  = (__half*)(A + (size_t)N * HDIM); // N*128 half
    float*  xs   = (float*)(Q16 + (size_t)N * HDIM);// N*8
    float*  agg  = xs + (size_t)N * 8;              // N*8
    float*  gsum = agg + (size_t)N * 8;             // G*128
    float*  gsq  = gsum + (size_t)G * HDIM;         // G*128
    float*  gpool= gsq + (size_t)G * HDIM;          // G*128
    float*  gcnt = gpool + (size_t)G * HDIM;        // G
    float*  dinv = gcnt + G;                        // N
    int* rowStart= (int*)(dinv + N);                // N+2
    unsigned int* EP = (unsigned int*)(rowStart + N + 2); // E
    int* col     = (int*)(EP + E);                  // E
    int* histG   = col + E;                         // NCHUNK*NB
    int* tot     = histG + (size_t)NCHUNK * NB;     // NB+2
    int* bucketBase = tot + NB + 2;                 // NB+2

    int gridN  = (N + 255) / 256;
    int gridNW = (N + 3) / 4;
    int gridGH = (G * HDIM + 255) / 256;
    int gridMM = (N + 63) / 64;

    // ---- CSR build (bucketed counting sort) ----
    hist_pass<<<NCHUNK, 256, 0, stream>>>(dstI, histG, E, NB);
    scan_chunks<<<NB, 512, 0, stream>>>(histG, tot, NCHUNK, NB);
    scan_tot_k<<<1, 512, 0, stream>>>(tot, bucketBase, rowStart, NB, N, E);
    add_base<<<((NCHUNK * NB) + 255) / 256, 256, 0, stream>>>(histG, bucketBase, NCHUNK * NB, NB);
    scatter_bkt<<<NCHUNK, 256, 0, stream>>>(srcI, dstI, histG, EP, E, NB);
    bucket_csr<<<NB, 512, 0, stream>>>(EP, bucketBase, rowStart, dinv, col, N);

    // per-graph node counts
    hipMemsetAsync(gcnt, 0, (size_t)G * 4, stream);
    count_nodes<<<gridN, 256, 0, stream>>>(batch, gcnt, N);

    // ---- block 1 (rank-7 aggregation) ----
    long long nx8 = (long long)N * 8;
    prep_xs<<<(int)((nx8 + 255) / 256), 256, 0, stream>>>(x, dinv, xs, nx8);
    agg7k<<<(N + 31) / 32, 256, 0, stream>>>(col, rowStart, xs, agg, N);
    hipMemsetAsync(gsum, 0, (size_t)G * HDIM * 4, stream);
    hipMemsetAsync(gsq, 0, (size_t)G * HDIM * 4, stream);
    l1post<<<gridNW, 512, 0, stream>>>(agg, W1, b1, dinv, batch, A, gsum, gsq, N);
    gstat<<<gridGH, 256, 0, stream>>>(gsum, gsq, gcnt, gn1a, G * HDIM);

    // ---- mm_h with fused layer-1 norm+relu, fp16 output ----
    mm_h_fused<<<gridMM, 256, 0, stream>>>(A, gsum, gsq, gn1a, gn1w, gn1b, batch,
                                           W2, dinv, Q16, N);

    // ---- block 2 (fp16 gather) ----
    hipMemsetAsync(gsum, 0, (size_t)G * HDIM * 4, stream);
    hipMemsetAsync(gsq, 0, (size_t)G * HDIM * 4, stream);
    node_agg2<<<gridNW, 256, 0, stream>>>(col, rowStart, Q16, dinv, b2, batch, A, gsum, gsq, N);
    gstat<<<gridGH, 256, 0, stream>>>(gsum, gsq, gcnt, gn2a, G * HDIM);

    // ---- layer-2 norm + relu + pool fused ----
    hipMemsetAsync(gpool, 0, (size_t)G * HDIM * 4, stream);
    node_norm_pool<<<gridNW, 256, 0, stream>>>(A, gsum, gsq, gn2a, gn2w, gn2b, batch, gpool, N);

    // ---- head ----
    head<<<G, 128, 0, stream>>>(gpool, gcnt, H1, hb1, H2, hb2, (float*)d_out, G);
}

// Round 5
// 544.857 us; speedup vs baseline: 10.7035x; 1.0321x over previous
//
#include <hip/hip_runtime.h>
#include <hip/hip_fp16.h>

#define EPSV 1e-5f
#define HDIM 128
#define BKT_SHIFT 9
#define BKT_SIZE 512
#define CHK 8192

// ================= CSR build: bucketed counting sort =================

__global__ __launch_bounds__(256) void hist_pass(const int* __restrict__ dst,
                                                 int* __restrict__ histG, int E, int NB) {
    __shared__ int h[BKT_SIZE];
    int t = threadIdx.x;
    for (int i = t; i < NB; i += 256) h[i] = 0;
    __syncthreads();
    int base = blockIdx.x * CHK;
    int end = min(base + CHK, E);
    for (int e = base + t; e < end; e += 256) atomicAdd(&h[dst[e] >> BKT_SHIFT], 1);
    __syncthreads();
    for (int i = t; i < NB; i += 256) histG[(size_t)blockIdx.x * NB + i] = h[i];
}

__global__ __launch_bounds__(512) void scan_chunks(int* __restrict__ histG,
                                                   int* __restrict__ tot,
                                                   int NCHUNK, int NB) {
    __shared__ int tmp[512];
    int b = blockIdx.x, t = threadIdx.x;
    int v = (t < NCHUNK) ? histG[(size_t)t * NB + b] : 0;
    tmp[t] = v;
    __syncthreads();
    for (int off = 1; off < 512; off <<= 1) {
        int x = (t >= off) ? tmp[t - off] : 0;
        __syncthreads();
        tmp[t] += x;
        __syncthreads();
    }
    if (t < NCHUNK) histG[(size_t)t * NB + b] = tmp[t] - v;
    if (t == 511) tot[b] = tmp[511];
}

__global__ __launch_bounds__(512) void scan_tot_k(const int* __restrict__ tot,
                                                  int* __restrict__ bucketBase,
                                                  int* __restrict__ rowStart,
                                                  int NB, int N, int E) {
    __shared__ int tmp[512];
    int t = threadIdx.x;
    int v = (t < NB) ? tot[t] : 0;
    tmp[t] = v;
    __syncthreads();
    for (int off = 1; off < 512; off <<= 1) {
        int x = (t >= off) ? tmp[t - off] : 0;
        __syncthreads();
        tmp[t] += x;
        __syncthreads();
    }
    if (t < NB) bucketBase[t] = tmp[t] - v;
    if (t == NB - 1) {
        bucketBase[NB] = tmp[t];
        rowStart[N] = E;
    }
}

__global__ __launch_bounds__(256) void add_base(int* __restrict__ histG,
                                                const int* __restrict__ bucketBase,
                                                int total, int NB) {
    int i = blockIdx.x * 256 + threadIdx.x;
    if (i < total) histG[i] += bucketBase[i % NB];
}

__global__ __launch_bounds__(256) void scatter_bkt(const int* __restrict__ src,
                                                   const int* __restrict__ dst,
                                                   const int* __restrict__ chunkOff,
                                                   unsigned int* __restrict__ EP,
                                                   int E, int NB) {
    __shared__ int cur[BKT_SIZE];
    int t = threadIdx.x, c = blockIdx.x;
    for (int i = t; i < NB; i += 256) cur[i] = chunkOff[(size_t)c * NB + i];
    __syncthreads();
    int base = c * CHK, end = min(base + CHK, E);
    for (int e = base + t; e < end; e += 256) {
        int d = dst[e];
        int b = d >> BKT_SHIFT;
        int pos = atomicAdd(&cur[b], 1);
        EP[pos] = (unsigned int)src[e] | ((unsigned int)(d & (BKT_SIZE - 1)) << 23);
    }
}

__global__ __launch_bounds__(512) void bucket_csr(const unsigned int* __restrict__ EP,
                                                  const int* __restrict__ bucketBase,
                                                  int* __restrict__ rowStart,
                                                  float* __restrict__ dinv,
                                                  int* __restrict__ col, int N) {
    __shared__ int cnt[BKT_SIZE];
    __shared__ int tmp[BKT_SIZE];
    int b = blockIdx.x, t = threadIdx.x;
    int ebase = bucketBase[b], eend = bucketBase[b + 1];
    cnt[t] = 0;
    __syncthreads();
    for (int e = ebase + t; e < eend; e += 512)
        atomicAdd(&cnt[(EP[e] >> 23) & 511], 1);
    __syncthreads();
    int v = cnt[t];
    tmp[t] = v;
    __syncthreads();
    for (int off = 1; off < 512; off <<= 1) {
        int x = (t >= off) ? tmp[t - off] : 0;
        __syncthreads();
        tmp[t] += x;
        __syncthreads();
    }
    int excl = tmp[t] - v;
    int n = (b << BKT_SHIFT) + t;
    if (n < N) {
        rowStart[n] = ebase + excl;
        dinv[n] = rsqrtf((float)v + 1.0f);
    }
    __syncthreads();
    cnt[t] = ebase + excl;
    __syncthreads();
    for (int e = ebase + t; e < eend; e += 512) {
        unsigned int p = EP[e];
        int ld = (p >> 23) & 511;
        int pos = atomicAdd(&cnt[ld], 1);
        col[pos] = (int)(p & 0x7FFFFFu);
    }
}

// ---------------- xs = dinv * x, padded [N][8]; also per-graph node counts ----------------
__global__ __launch_bounds__(256) void prep_xs(const float* __restrict__ x,
                                               const float* __restrict__ dinv,
                                               const int* __restrict__ batch,
                                               float* __restrict__ xs,
                                               float* __restrict__ gcnt, long long total) {
    long long idx = (long long)blockIdx.x * 256 + threadIdx.x;
    if (idx >= total) return;
    int n = (int)(idx >> 3), k = (int)(idx & 7);
    xs[idx] = (k < 7) ? x[(long long)n * 7 + k] * dinv[n] : 0.f;
    if (k == 7) unsafeAtomicAdd(&gcnt[batch[n]], 1.0f);
}

// ---------------- layer-1 aggregation on 8-wide rows (8 threads per node) ----------------
__global__ __launch_bounds__(256) void agg7k(const int* __restrict__ col,
                                             const int* __restrict__ rowStart,
                                             const float* __restrict__ xs,
                                             float* __restrict__ agg, int N) {
    int tid = threadIdx.x;
    int node = blockIdx.x * 32 + (tid >> 3);
    int j = tid & 7;
    if (node >= N) return;
    float acc = xs[(size_t)node * 8 + j];
    int rs = rowStart[node], re = rowStart[node + 1];
    int e = rs;
    for (; e + 3 < re; e += 4) {
        int s0 = col[e], s1 = col[e + 1], s2 = col[e + 2], s3 = col[e + 3];
        acc += xs[(size_t)s0 * 8 + j] + xs[(size_t)s1 * 8 + j]
             + xs[(size_t)s2 * 8 + j] + xs[(size_t)s3 * 8 + j];
    }
    for (; e < re; e++) acc += xs[(size_t)col[e] * 8 + j];
    agg[(size_t)node * 8 + j] = acc;
}

// ---------------- layer-1 post: A = dinv*(agg@W1)+b1, accumulate stats ----------------
__global__ __launch_bounds__(512) void l1post(const float* __restrict__ agg,
                                              const float* __restrict__ W1,
                                              const float* __restrict__ b1,
                                              const float* __restrict__ dinv,
                                              const int* __restrict__ batch,
                                              float* __restrict__ A,
                                              float* __restrict__ gsum,
                                              float* __restrict__ gsq, int N) {
    __shared__ float w1s[7 * HDIM];
    __shared__ float red_s[4][HDIM], red_q[4][HDIM];
    __shared__ int bsh[4];
    int t = threadIdx.x;
    for (int i = t; i < 7 * HDIM; i += 512) w1s[i] = W1[i];
    int wib = t >> 7, c = t & 127;
    int n = blockIdx.x * 4 + wib;
    __syncthreads();
    bool act = (n < N);
    float v = 0.f;
    int b = -1;
    if (act) {
        b = batch[n];
        const float* ar = agg + (size_t)n * 8;
        float s = 0.f;
#pragma unroll
        for (int k = 0; k < 7; k++) s += ar[k] * w1s[k * HDIM + c];
        v = s * dinv[n] + b1[c];
        A[(size_t)n * HDIM + c] = v;
    }
    if (c == 0) bsh[wib] = act ? b : -1;
    red_s[wib][c] = v;
    red_q[wib][c] = v * v;
    __syncthreads();
    int b0 = bsh[0];
    bool uni = (b0 >= 0) && (bsh[1] == b0) && (bsh[2] == b0) && (bsh[3] == b0);
    if (uni) {
        if (wib == 0) {
            float vs = red_s[0][c] + red_s[1][c] + red_s[2][c] + red_s[3][c];
            float qs = red_q[0][c] + red_q[1][c] + red_q[2][c] + red_q[3][c];
            unsafeAtomicAdd(&gsum[(size_t)b0 * HDIM + c], vs);
            unsafeAtomicAdd(&gsq[(size_t)b0 * HDIM + c], qs);
        }
    } else if (act) {
        unsafeAtomicAdd(&gsum[(size_t)b * HDIM + c], v);
        unsafeAtomicAdd(&gsq[(size_t)b * HDIM + c], v * v);
    }
}

// ---------------- per-(graph,channel): sums -> mean, inv-std ----------------
__global__ __launch_bounds__(256) void gstat(float* __restrict__ gsum,
                                             float* __restrict__ gsq,
                                             const float* __restrict__ gcnt,
                                             const float* __restrict__ alpha, int total) {
    int i = blockIdx.x * 256 + threadIdx.x;
    if (i < total) {
        int g = i >> 7, c = i & 127;
        float cnt = fmaxf(gcnt[g], 1.f);
        float mean = gsum[i] / cnt;
        float m2 = gsq[i] / cnt;
        float a = alpha[c];
        float var = m2 + mean * mean * (a * a - 2.f * a);
        gsum[i] = mean;
        gsq[i] = rsqrtf(fmaxf(var, 0.f) + EPSV);
    }
}

// ---------------- hidden matmul with fused layer-1 norm+relu on load, fp16 out ----------------
__global__ __launch_bounds__(256) void mm_h_fused(const float* __restrict__ A,
                                                  const float* __restrict__ gmean,
                                                  const float* __restrict__ gistd,
                                                  const float* __restrict__ alpha,
                                                  const float* __restrict__ w,
                                                  const float* __restrict__ bb,
                                                  const int* __restrict__ batch,
                                                  const float* __restrict__ W,
                                                  const float* __restrict__ dinv,
                                                  __half* __restrict__ Q, int N) {
    __shared__ float xs[64][65];
    __shared__ __align__(16) float ws[64][HDIM];
    __shared__ float pA[HDIM], pW[HDIM], pB[HDIM];
    int t = threadIdx.x;
    for (int i = t; i < HDIM; i += 256) { pA[i] = alpha[i]; pW[i] = w[i]; pB[i] = bb[i]; }
    int tx = t & 15;
    int ty = t >> 4;
    int n0 = blockIdx.x * 64;
    float acc[4][8];
#pragma unroll
    for (int i = 0; i < 4; i++)
#pragma unroll
        for (int j = 0; j < 8; j++) acc[i][j] = 0.f;

    for (int s = 0; s < 2; ++s) {
        __syncthreads();
        for (int i = t; i < 64 * 16; i += 256) {
            int nn = i >> 4;
            int kk = (i & 15) * 4;
            int gn = n0 + nn;
            float4 v = make_float4(0.f, 0.f, 0.f, 0.f);
            if (gn < N) {
                v = *(const float4*)(A + (size_t)gn * HDIM + s * 64 + kk);
                int b = batch[gn];
                int c = s * 64 + kk;
                float4 m = *(const float4*)(gmean + (size_t)b * HDIM + c);
                float4 is = *(const float4*)(gistd + (size_t)b * HDIM + c);
                v.x = fmaxf(pW[c] * (v.x - pA[c] * m.x) * is.x + pB[c], 0.f);
                v.y = fmaxf(pW[c + 1] * (v.y - pA[c + 1] * m.y) * is.y + pB[c + 1], 0.f);
                v.z = fmaxf(pW[c + 2] * (v.z - pA[c + 2] * m.z) * is.z + pB[c + 2], 0.f);
                v.w = fmaxf(pW[c + 3] * (v.w - pA[c + 3] * m.w) * is.w + pB[c + 3], 0.f);
            }
            xs[nn][kk] = v.x; xs[nn][kk + 1] = v.y; xs[nn][kk + 2] = v.z; xs[nn][kk + 3] = v.w;
        }
        for (int i = t; i < 64 * 32; i += 256) {
            int kk = i >> 5;
            int c = (i & 31) * 4;
            *(float4*)&ws[kk][c] = *(const float4*)(W + (size_t)(s * 64 + kk) * HDIM + c);
        }
        __syncthreads();
#pragma unroll 8
        for (int kk = 0; kk < 64; ++kk) {
            float xv[4];
#pragma unroll
            for (int i = 0; i < 4; i++) xv[i] = xs[ty * 4 + i][kk];
            float4 w0 = *(const float4*)&ws[kk][tx * 4];
            float4 w1 = *(const float4*)&ws[kk][64 + tx * 4];
#pragma unroll
            for (int i = 0; i < 4; i++) {
                acc[i][0] += xv[i] * w0.x; acc[i][1] += xv[i] * w0.y;
                acc[i][2] += xv[i] * w0.z; acc[i][3] += xv[i] * w0.w;
                acc[i][4] += xv[i] * w1.x; acc[i][5] += xv[i] * w1.y;
                acc[i][6] += xv[i] * w1.z; acc[i][7] += xv[i] * w1.w;
            }
        }
    }
#pragma unroll
    for (int i = 0; i < 4; i++) {
        int gn = n0 + ty * 4 + i;
        if (gn >= N) continue;
        float dv = dinv[gn];
        __half2* q0 = (__half2*)(Q + (size_t)gn * HDIM + tx * 4);
        __half2* q1 = (__half2*)(Q + (size_t)gn * HDIM + 64 + tx * 4);
        q0[0] = __floats2half2_rn(acc[i][0] * dv, acc[i][1] * dv);
        q0[1] = __floats2half2_rn(acc[i][2] * dv, acc[i][3] * dv);
        q1[0] = __floats2half2_rn(acc[i][4] * dv, acc[i][5] * dv);
        q1[1] = __floats2half2_rn(acc[i][6] * dv, acc[i][7] * dv);
    }
}

// ---------------- fp16 row load: 4 channels (8B) ----------------
__device__ __forceinline__ float4 qrow4(const __half* __restrict__ Q, int e, int c4) {
    uint2 u = *(const uint2*)(Q + (size_t)e * HDIM + c4);
    float2 f0 = __half22float2(*(__half2*)&u.x);
    float2 f1 = __half22float2(*(__half2*)&u.y);
    return make_float4(f0.x, f0.y, f1.x, f1.y);
}

// ---------------- layer-2 CSR gather: half-wave per edge stream, 4ch/lane ----------------
__global__ __launch_bounds__(256) void node_agg2(const int* __restrict__ col,
                                                 const int* __restrict__ rowStart,
                                                 const __half* __restrict__ Q,
                                                 const float* __restrict__ dinv,
                                                 const float* __restrict__ bias,
                                                 const int* __restrict__ batch,
                                                 __half* __restrict__ A2,
                                                 float* __restrict__ gsum,
                                                 float* __restrict__ gsq, int N) {
    __shared__ __align__(16) float sv[4][HDIM];
    __shared__ __align__(16) float sq[4][HDIM];
    __shared__ int bsh[4];
    int wib = threadIdx.x >> 6;
    int lane = threadIdx.x & 63;
    int half = lane >> 5;
    int l = lane & 31;
    int c4 = l * 4;
    int n = blockIdx.x * 4 + wib;
    bool active = (n < N);
    float4 acc = make_float4(0.f, 0.f, 0.f, 0.f);
    int b = -1;
    if (active) {
        b = batch[n];
        int rs = rowStart[n], re = rowStart[n + 1];
        if (half == 0) acc = qrow4(Q, n, c4);          // self term
        int j = rs + half;
        for (; j + 6 < re; j += 8) {
            int e0 = col[j], e1 = col[j + 2], e2 = col[j + 4], e3 = col[j + 6];
            float4 r0 = qrow4(Q, e0, c4);
            float4 r1 = qrow4(Q, e1, c4);
            float4 r2 = qrow4(Q, e2, c4);
            float4 r3 = qrow4(Q, e3, c4);
            acc.x += (r0.x + r1.x) + (r2.x + r3.x);
            acc.y += (r0.y + r1.y) + (r2.y + r3.y);
            acc.z += (r0.z + r1.z) + (r2.z + r3.z);
            acc.w += (r0.w + r1.w) + (r2.w + r3.w);
        }
        for (; j < re; j += 2) {
            float4 r = qrow4(Q, col[j], c4);
            acc.x += r.x; acc.y += r.y; acc.z += r.z; acc.w += r.w;
        }
        // combine even/odd edge streams
        acc.x += __shfl_xor(acc.x, 32);
        acc.y += __shfl_xor(acc.y, 32);
        acc.z += __shfl_xor(acc.z, 32);
        acc.w += __shfl_xor(acc.w, 32);
        float dv = dinv[n];
        acc.x = acc.x * dv + bias[c4];
        acc.y = acc.y * dv + bias[c4 + 1];
        acc.z = acc.z * dv + bias[c4 + 2];
        acc.w = acc.w * dv + bias[c4 + 3];
        if (half == 0) {
            __half2 o0 = __floats2half2_rn(acc.x, acc.y);
            __half2 o1 = __floats2half2_rn(acc.z, acc.w);
            uint2 u;
            u.x = *(unsigned int*)&o0;
            u.y = *(unsigned int*)&o1;
            *(uint2*)(A2 + (size_t)n * HDIM + c4) = u;
        }
    }
    if (lane == 0) bsh[wib] = active ? b : -1;
    if (half == 0) {
        float4 z = active ? acc : make_float4(0.f, 0.f, 0.f, 0.f);
        *(float4*)&sv[wib][c4] = z;
        *(float4*)&sq[wib][c4] = make_float4(z.x * z.x, z.y * z.y, z.z * z.z, z.w * z.w);
    }
    __syncthreads();
    int b0 = bsh[0];
    bool uni = (b0 >= 0) && (bsh[1] == b0) && (bsh[2] == b0) && (bsh[3] == b0);
    if (uni) {
        if (wib == 0 && half == 0) {
#pragma unroll
            for (int k = 0; k < 4; k++) {
                int c = c4 + k;
                float vs = sv[0][c] + sv[1][c] + sv[2][c] + sv[3][c];
                float qs = sq[0][c] + sq[1][c] + sq[2][c] + sq[3][c];
                unsafeAtomicAdd(&gsum[(size_t)b0 * HDIM + c], vs);
                unsafeAtomicAdd(&gsq[(size_t)b0 * HDIM + c], qs);
            }
        }
    } else if (active && half == 0) {
        float va[4] = {acc.x, acc.y, acc.z, acc.w};
#pragma unroll
        for (int k = 0; k < 4; k++) {
            int c = c4 + k;
            unsafeAtomicAdd(&gsum[(size_t)b * HDIM + c], va[k]);
            unsafeAtomicAdd(&gsq[(size_t)b * HDIM + c], va[k] * va[k]);
        }
    }
}

// ---------------- layer-2 normalize+relu fused with pool atomics (wave per node) ----------------
__global__ __launch_bounds__(256) void node_norm_pool(const __half* __restrict__ A2,
                                                      const float* __restrict__ gmean,
                                                      const float* __restrict__ gistd,
                                                      const float* __restrict__ alpha,
                                                      const float* __restrict__ w,
                                                      const float* __restrict__ bb,
                                                      const int* __restrict__ batch,
                                                      float* __restrict__ gpool, int N) {
    __shared__ float sv[4][HDIM];
    __shared__ int bsh[4];
    int wib = threadIdx.x >> 6, lane = threadIdx.x & 63;
    int c = lane * 2;
    int n = blockIdx.x * 4 + wib;
    bool active = (n < N);
    float2 y = make_float2(0.f, 0.f);
    int b = -1;
    if (active) {
        b = batch[n];
        float2 v = __half22float2(*(const __half2*)(A2 + (size_t)n * HDIM + c));
        float2 m = *(const float2*)(gmean + (size_t)b * HDIM + c);
        float2 is = *(const float2*)(gistd + (size_t)b * HDIM + c);
        y.x = fmaxf(w[c] * (v.x - alpha[c] * m.x) * is.x + bb[c], 0.f);
        y.y = fmaxf(w[c + 1] * (v.y - alpha[c + 1] * m.y) * is.y + bb[c + 1], 0.f);
    }
    if (lane == 0) bsh[wib] = active ? b : -1;
    sv[wib][c] = y.x; sv[wib][c + 1] = y.y;
    __syncthreads();
    int b0 = bsh[0];
    bool uni = (b0 >= 0) && (bsh[1] == b0) && (bsh[2] == b0) && (bsh[3] == b0);
    if (uni) {
        if (wib == 0) {
            float vx = sv[0][c] + sv[1][c] + sv[2][c] + sv[3][c];
            float vy = sv[0][c + 1] + sv[1][c + 1] + sv[2][c + 1] + sv[3][c + 1];
            unsafeAtomicAdd(&gpool[(size_t)b0 * HDIM + c], vx);
            unsafeAtomicAdd(&gpool[(size_t)b0 * HDIM + c + 1], vy);
        }
    } else if (active) {
        unsafeAtomicAdd(&gpool[(size_t)b * HDIM + c], y.x);
        unsafeAtomicAdd(&gpool[(size_t)b * HDIM + c + 1], y.y);
    }
}

// ---------------- head ----------------
__global__ __launch_bounds__(128) void head(const float* __restrict__ gpool,
                                            const float* __restrict__ gcnt,
                                            const float* __restrict__ H1,
                                            const float* __restrict__ hb1,
                                            const float* __restrict__ H2,
                                            const float* __restrict__ hb2,
                                            float* __restrict__ out, int G) {
    __shared__ float gv[HDIM];
    __shared__ float tv[HDIM];
    __shared__ float r0[HDIM], r1[HDIM];
    int g = blockIdx.x;
    int c = threadIdx.x;
    float cnt = fmaxf(gcnt[g], 1.0f);
    gv[c] = gpool[(long long)g * HDIM + c] / cnt;
    __syncthreads();
    float s = hb1[c];
    for (int k = 0; k < HDIM; k++) s += gv[k] * H1[k * HDIM + c];
    tv[c] = fmaxf(s, 0.f);
    __syncthreads();
    r0[c] = tv[c] * H2[c * 2 + 0];
    r1[c] = tv[c] * H2[c * 2 + 1];
    __syncthreads();
    for (int off = 64; off > 0; off >>= 1) {
        if (c < off) { r0[c] += r0[c + off]; r1[c] += r1[c + off]; }
        __syncthreads();
    }
    if (c == 0) {
        out[(long long)g * 2 + 0] = r0[0] + hb2[0];
        out[(long long)g * 2 + 1] = r1[0] + hb2[1];
    }
}

extern "C" void kernel_launch(void* const* d_in, const int* in_sizes, int n_in,
                              void* d_out, int out_size, void* d_ws, size_t ws_size,
                              hipStream_t stream) {
    const float* x    = (const float*)d_in[0];
    const int*   ei   = (const int*)d_in[1];
    const int*   batch= (const int*)d_in[2];
    const float* W1   = (const float*)d_in[4];
    const float* b1   = (const float*)d_in[5];
    const float* gn1w = (const float*)d_in[6];
    const float* gn1b = (const float*)d_in[7];
    const float* gn1a = (const float*)d_in[8];
    const float* W2   = (const float*)d_in[9];
    const float* b2   = (const float*)d_in[10];
    const float* gn2w = (const float*)d_in[11];
    const float* gn2b = (const float*)d_in[12];
    const float* gn2a = (const float*)d_in[13];
    const float* H1   = (const float*)d_in[14];
    const float* hb1  = (const float*)d_in[15];
    const float* H2   = (const float*)d_in[16];
    const float* hb2  = (const float*)d_in[17];

    int N = in_sizes[0] / 7;
    int E = in_sizes[1] / 2;
    int G = out_size / 2;
    const int* srcI = ei;
    const int* dstI = ei + E;

    int NB = (N + BKT_SIZE - 1) >> BKT_SHIFT;
    int NCHUNK = (E + CHK - 1) / CHK;

    // workspace layout
    float*  A     = (float*)d_ws;                    // N*128 fp32 (layer1 pre-norm)
    __half* A2    = (__half*)A;                      // aliases A (layer2 pre-norm, fp16)
    __half* Q16   = (__half*)(A + (size_t)N * HDIM); // N*128 half
    float*  xs    = (float*)(Q16 + (size_t)N * HDIM);// N*8
    float*  agg   = xs + (size_t)N * 8;              // N*8
    float*  gsum1 = agg + (size_t)N * 8;             // G*128
    float*  gsq1  = gsum1 + (size_t)G * HDIM;        // G*128
    float*  gsum2 = gsq1 + (size_t)G * HDIM;         // G*128
    float*  gsq2  = gsum2 + (size_t)G * HDIM;        // G*128
    float*  gpool = gsq2 + (size_t)G * HDIM;         // G*128
    float*  gcnt  = gpool + (size_t)G * HDIM;        // G
    float*  dinv  = gcnt + G;                        // N
    int* rowStart = (int*)(dinv + N);                // N+2
    unsigned int* EP = (unsigned int*)(rowStart + N + 2); // E
    int* col      = (int*)(EP + E);                  // E
    int* histG    = col + E;                         // NCHUNK*NB
    int* tot      = histG + (size_t)NCHUNK * NB;     // NB+2
    int* bucketBase = tot + NB + 2;                  // NB+2

    int gridNW = (N + 3) / 4;
    int gridGH = (G * HDIM + 255) / 256;
    int gridMM = (N + 63) / 64;

    // single upfront memset: gsum1,gsq1,gsum2,gsq2,gpool,gcnt
    hipMemsetAsync(gsum1, 0, ((size_t)G * HDIM * 5 + G) * 4, stream);

    // ---- CSR build ----
    hist_pass<<<NCHUNK, 256, 0, stream>>>(dstI, histG, E, NB);
    scan_chunks<<<NB, 512, 0, stream>>>(histG, tot, NCHUNK, NB);
    scan_tot_k<<<1, 512, 0, stream>>>(tot, bucketBase, rowStart, NB, N, E);
    add_base<<<((NCHUNK * NB) + 255) / 256, 256, 0, stream>>>(histG, bucketBase, NCHUNK * NB, NB);
    scatter_bkt<<<NCHUNK, 256, 0, stream>>>(srcI, dstI, histG, EP, E, NB);
    bucket_csr<<<NB, 512, 0, stream>>>(EP, bucketBase, rowStart, dinv, col, N);

    // ---- block 1 (rank-7 aggregation) ----
    long long nx8 = (long long)N * 8;
    prep_xs<<<(int)((nx8 + 255) / 256), 256, 0, stream>>>(x, dinv, batch, xs, gcnt, nx8);
    agg7k<<<(N + 31) / 32, 256, 0, stream>>>(col, rowStart, xs, agg, N);
    l1post<<<gridNW, 512, 0, stream>>>(agg, W1, b1, dinv, batch, A, gsum1, gsq1, N);
    gstat<<<gridGH, 256, 0, stream>>>(gsum1, gsq1, gcnt, gn1a, G * HDIM);

    // ---- mm_h with fused layer-1 norm+relu, fp16 output ----
    mm_h_fused<<<gridMM, 256, 0, stream>>>(A, gsum1, gsq1, gn1a, gn1w, gn1b, batch,
                                           W2, dinv, Q16, N);

    // ---- block 2 (fp16 gather, half-wave edge streams) ----
    node_agg2<<<gridNW, 256, 0, stream>>>(col, rowStart, Q16, dinv, b2, batch, A2,
                                          gsum2, gsq2, N);
    gstat<<<gridGH, 256, 0, stream>>>(gsum2, gsq2, gcnt, gn2a, G * HDIM);

    // ---- layer-2 norm + relu + pool fused ----
    node_norm_pool<<<gridNW, 256, 0, stream>>>(A2, gsum2, gsq2, gn2a, gn2w, gn2b, batch, gpool, N);

    // ---- head ----
    head<<<G, 128, 0, stream>>>(gpool, gcnt, H1, hb1, H2, hb2, (float*)d_out, G);
}